// Round 4
// baseline (7214.766 us; speedup 1.0000x reference)
//
#include <hip/hip_runtime.h>
#include <cmath>

typedef unsigned long long u64;
typedef unsigned int u32;

constexpr int CB = 2;
constexpr int CC = 1024;
constexpr int CH = 50;
constexpr int CW = 76;
constexpr int CHW = CH * CW;        // 3800
constexpr int CA = 15;
constexpr int NANCH = CHW * CA;     // 57000
constexpr int PRE = 2000;
constexpr int POST = 300;
constexpr int NDET = 100;
constexpr int NCLS = 1600;
constexpr int GN = 1605;            // 1601 cls logits + 4 box deltas
constexpr float RPN_T = 0.7f;
constexpr float DET_T = 0.5f;
constexpr float SCORE_T_ = 0.05f;
constexpr float CLIPLOG = 4.135166556742356f;

__device__ __forceinline__ u32 fkey(float f) {
  u32 u = __float_as_uint(f);
  return (u & 0x80000000u) ? ~u : (u | 0x80000000u);
}

// ---------------- RPN 3x3 conv partials (no bias/relu), pixel-major ----------------
// v3: LDS-staged inputs (broadcast reads) + weights (2-way-free per-lane reads), 2 oc/thread,
// fully unrolled 8x3 (ic,ky) so all ds_reads are base+immediate (no VALU addr math).
// Grid (8 octiles * nks, 50 y, 2 b), 256 thr = 4 waves x 19px, 128 oc/block.
// Block computes ic in [ks*klen, ks*klen+klen). ks=0 -> t, ks=1 -> p1.
__global__ __launch_bounds__(256) void conv3x3p(
    const float* __restrict__ feat, const float* __restrict__ wgt,
    float* __restrict__ t, float* __restrict__ p1, int klen) {
  __shared__ float wl[128][73];     // [oc_local][ic_local*9+tap]; stride 73 words -> 2-way (free)
  __shared__ float inl[8][3][80];   // [ic][ky][x+1], x in [-1,76]
  const int bx = blockIdx.x;
  const int octile = bx & 7, ks = bx >> 3;
  const int y = blockIdx.y, b = blockIdx.z;
  const int oc0 = octile * 128;
  const int tid = threadIdx.x;
  const int lane = tid & 63;
  const int wid = tid >> 6;
  const int x0 = wid * 19;
  float acc0[19], acc1[19];
#pragma unroll
  for (int p = 0; p < 19; ++p) { acc0[p] = 0.f; acc1[p] = 0.f; }
  const float* fb = feat + (size_t)b * CC * CHW;
  const int icbeg = ks * klen;
  for (int ic0 = icbeg; ic0 < icbeg + klen; ic0 += 8) {
    __syncthreads();
    // stage weights: 128 oc x 72 taps; coalesced global, conflict-free LDS writes
    for (int o = wid; o < 128; o += 4) {
      const float* wrow = wgt + (size_t)(oc0 + o) * 9216 + ic0 * 9;
      wl[o][lane] = wrow[lane];
      if (lane < 8) wl[o][64 + lane] = wrow[64 + lane];
    }
    // stage inputs: 8 ic x 3 rows x 78 (idx 0..77 = x -1..76), zero halo
    for (int l = tid; l < 8 * 3 * 78; l += 256) {
      int ic = l / 234;
      int rem = l - ic * 234;
      int r = rem / 78;
      int xx = rem - r * 78 - 1;
      int yy = y + r - 1;
      float v = 0.f;
      if (yy >= 0 && yy < CH && xx >= 0 && xx < CW)
        v = fb[(size_t)(ic0 + ic) * CHW + yy * CW + xx];
      inl[ic][r][xx + 1] = v;
    }
    __syncthreads();
#pragma unroll
    for (int ic = 0; ic < 8; ++ic) {
#pragma unroll
      for (int ky = 0; ky < 3; ++ky) {
        float inv[21];
#pragma unroll
        for (int k = 0; k < 21; ++k) inv[k] = inl[ic][ky][x0 + k];  // broadcast, imm offset
        const int c = ic * 9 + ky * 3;
        const float w0a = wl[lane][c], w1a = wl[lane][c + 1], w2a = wl[lane][c + 2];
        const float w0b = wl[64 + lane][c], w1b = wl[64 + lane][c + 1], w2b = wl[64 + lane][c + 2];
#pragma unroll
        for (int p = 0; p < 19; ++p) {
          acc0[p] = fmaf(w0a, inv[p], acc0[p]);
          acc0[p] = fmaf(w1a, inv[p + 1], acc0[p]);
          acc0[p] = fmaf(w2a, inv[p + 2], acc0[p]);
          acc1[p] = fmaf(w0b, inv[p], acc1[p]);
          acc1[p] = fmaf(w1b, inv[p + 1], acc1[p]);
          acc1[p] = fmaf(w2b, inv[p + 2], acc1[p]);
        }
      }
    }
  }
  float* pp = (ks == 0) ? t : p1;
#pragma unroll
  for (int p = 0; p < 19; ++p) {
    int x = x0 + p;
    float* tp = pp + ((size_t)b * CHW + y * CW + x) * CC + oc0;
    tp[lane] = acc0[p];
    tp[64 + lane] = acc1[p];
  }
}

// ---------------- t = relu(p0 + (two? p1:0) + bias), in-place on p0 ----------------
__global__ __launch_bounds__(256) void reduce_br(
    const float* __restrict__ p1, const float* __restrict__ bias,
    float* __restrict__ t, int two) {
  size_t i = ((size_t)blockIdx.x * 256 + threadIdx.x) * 4;
  float4 a = *reinterpret_cast<const float4*>(t + i);
  int oc = (int)(i & (CC - 1));
  const float4 bv = *reinterpret_cast<const float4*>(bias + oc);
  float4 r;
  if (two) {
    const float4 c = *reinterpret_cast<const float4*>(p1 + i);
    r.x = a.x + c.x + bv.x; r.y = a.y + c.y + bv.y;
    r.z = a.z + c.z + bv.z; r.w = a.w + c.w + bv.w;
  } else {
    r.x = a.x + bv.x; r.y = a.y + bv.y; r.z = a.z + bv.z; r.w = a.w + bv.w;
  }
  r.x = fmaxf(r.x, 0.f); r.y = fmaxf(r.y, 0.f);
  r.z = fmaxf(r.z, 0.f); r.w = fmaxf(r.w, 0.f);
  *reinterpret_cast<float4*>(t + i) = r;
}

// ---------------- obj (15) & delta (60) 1x1 heads ----------------
// grid 475 (16 px each), 256 threads = 64 o-lanes x 4 pixel groups
__global__ __launch_bounds__(256) void heads(
    const float* __restrict__ t,
    const float* __restrict__ ow, const float* __restrict__ ob,
    const float* __restrict__ dw, const float* __restrict__ db,
    float* __restrict__ scores, float* __restrict__ deltas) {
  __shared__ float tl[16][64];
  __shared__ float wl[64][81];  // [k][o] o<75
  const int tid = threadIdx.x;
  const int px0 = blockIdx.x * 16;
  const int lo = tid & 63, pg = tid >> 6;
  float accA[4] = {0, 0, 0, 0}, accB[4] = {0, 0, 0, 0};
  for (int kc = 0; kc < CC; kc += 64) {
    __syncthreads();
    for (int l = tid; l < 16 * 64; l += 256) {
      int p = l >> 6, k = l & 63;
      tl[p][k] = t[(size_t)(px0 + p) * CC + kc + k];
    }
    for (int l = tid; l < 75 * 64; l += 256) {
      int o = l >> 6, k = l & 63;
      wl[k][o] = (o < 15) ? ow[o * CC + kc + k] : dw[(o - 15) * CC + kc + k];
    }
    __syncthreads();
#pragma unroll 8
    for (int k = 0; k < 64; ++k) {
      float w1 = wl[k][lo];
      float w2 = (lo < 11) ? wl[k][64 + lo] : 0.f;
#pragma unroll
      for (int p = 0; p < 4; ++p) {
        float tv = tl[pg * 4 + p][k];
        accA[p] = fmaf(w1, tv, accA[p]);
        accB[p] = fmaf(w2, tv, accB[p]);
      }
    }
  }
#pragma unroll
  for (int p = 0; p < 4; ++p) {
    int px = px0 + pg * 4 + p;
    int b = px / CHW, pix = px - b * CHW;
    {
      int o = lo;
      float v = accA[p];
      if (o < 15) {
        scores[(size_t)b * NANCH + (size_t)pix * CA + o] = v + ob[o];
      } else {
        int oo = o - 15;
        deltas[((size_t)b * NANCH + (size_t)pix * CA + (oo >> 2)) * 4 + (oo & 3)] = v + db[oo];
      }
    }
    if (lo < 11) {
      int oo = 64 + lo - 15;  // 49..59
      deltas[((size_t)b * NANCH + (size_t)pix * CA + (oo >> 2)) * 4 + (oo & 3)] = accB[p] + db[oo];
    }
  }
}

// ---------------- feat NCHW -> NHWC transpose (for coalesced roi_align) ----------------
__global__ __launch_bounds__(256) void transp(const float* __restrict__ in, float* __restrict__ outT) {
  __shared__ float tile[32][33];
  int b = blockIdx.z;
  int p0 = blockIdx.x * 32, c0 = blockIdx.y * 32;
  int tx = threadIdx.x, ty = threadIdx.y;
  for (int i = ty; i < 32; i += 8) {
    int p = p0 + tx;
    tile[i][tx] = (p < CHW) ? in[((size_t)b * CC + c0 + i) * CHW + p] : 0.f;
  }
  __syncthreads();
  for (int i = ty; i < 32; i += 8) {
    int p = p0 + i;
    if (p < CHW) outT[((size_t)b * CHW + p) * CC + c0 + tx] = tile[tx][i];
  }
}

// ---------------- exact top-2000 (radix threshold + bitonic sort) + proposal decode + clip ------
// grid 2 (per image), 1024 threads
__global__ __launch_bounds__(1024) void topk_props(
    const float* __restrict__ scores, const float* __restrict__ deltas,
    const int* __restrict__ isz, float* __restrict__ selB) {
  const int img = blockIdx.x;
  const int tid = threadIdx.x;
  const float* sc = scores + (size_t)img * NANCH;
  __shared__ u32 hist[256];
  __shared__ u32 s_prefix, s_need, s_cnt;
  __shared__ u64 arr[4096];

  u32 prefix = 0, need = PRE;
  for (int byte = 3; byte >= 0; --byte) {
    if (tid < 256) hist[tid] = 0;
    __syncthreads();
    for (int i = tid; i < NANCH; i += 1024) {
      u32 key = fkey(sc[i]);
      bool ok = (byte == 3) || ((key >> (8 * byte + 8)) == prefix);
      if (ok) atomicAdd(&hist[(key >> (8 * byte)) & 255], 1u);
    }
    __syncthreads();
    if (tid == 0) {
      u32 cum = 0;
      int bin;
      for (bin = 255; bin >= 0; --bin) {
        cum += hist[bin];
        if (cum >= need) break;
      }
      s_need = need - (cum - hist[bin]);
      s_prefix = (prefix << 8) | (u32)bin;
    }
    __syncthreads();
    prefix = s_prefix;
    need = s_need;
    __syncthreads();
  }
  const u32 T = prefix;  // count(key>T) < PRE <= count(key>=T)
  if (tid == 0) s_cnt = 0;
  __syncthreads();
  for (int i = tid; i < NANCH; i += 1024) {
    u32 key = fkey(sc[i]);
    if (key >= T) {
      u32 p = atomicAdd(&s_cnt, 1u);
      if (p < 4096) arr[p] = ((u64)(~key) << 32) | (u32)i;  // ascending rank = score desc, idx asc
    }
  }
  __syncthreads();
  int n = (int)(s_cnt < 4096u ? s_cnt : 4096u);
  for (int i = tid; i < 4096; i += 1024)
    if (i >= n) arr[i] = ~0ULL;
  __syncthreads();
  for (int kk = 2; kk <= 4096; kk <<= 1) {
    for (int j = kk >> 1; j > 0; j >>= 1) {
      for (int i = tid; i < 4096; i += 1024) {
        int ixj = i ^ j;
        if (ixj > i) {
          u64 a = arr[i], bb = arr[ixj];
          bool up = ((i & kk) == 0);
          if ((a > bb) == up) { arr[i] = bb; arr[ixj] = a; }
        }
      }
      __syncthreads();
    }
  }
  // decode anchor + apply deltas + clip for the top PRE (sorted)
  const float h_img = (float)isz[img * 2 + 0];
  const float w_img = (float)isz[img * 2 + 1];
  const float* dl = deltas + (size_t)img * NANCH * 4;
  for (int k = tid; k < PRE; k += 1024) {
    u32 idx = (u32)arr[k];
    int aa = (int)(idx % 15u);
    int p = (int)(idx / 15u);
    int xx = p % CW, yy = p / CW;
    double szd = 32.0 * (double)(1 << (aa / 3));
    double rr = 0.5 * (double)(1 << (aa % 3));
    double wd = szd * sqrt(1.0 / rr);
    double hd = wd * rr;
    float ax1 = (float)(xx * 16) + (float)(-wd * 0.5);
    float ax2 = (float)(xx * 16) + (float)(wd * 0.5);
    float ay1 = (float)(yy * 16) + (float)(-hd * 0.5);
    float ay2 = (float)(yy * 16) + (float)(hd * 0.5);
    float aw = ax2 - ax1, ah = ay2 - ay1;
    float cx = ax1 + 0.5f * aw, cy = ay1 + 0.5f * ah;
    float d0 = dl[(size_t)idx * 4 + 0], d1 = dl[(size_t)idx * 4 + 1];
    float d2 = dl[(size_t)idx * 4 + 2], d3 = dl[(size_t)idx * 4 + 3];
    float dwv = fminf(d2, CLIPLOG), dhv = fminf(d3, CLIPLOG);
    float pcx = d0 * aw + cx, pcy = d1 * ah + cy;
    float pw = expf(dwv) * aw, ph = expf(dhv) * ah;
    float x1 = pcx - 0.5f * pw, y1 = pcy - 0.5f * ph;
    float x2 = pcx + 0.5f * pw, y2 = pcy + 0.5f * ph;
    x1 = fminf(fmaxf(x1, 0.f), w_img);
    y1 = fminf(fmaxf(y1, 0.f), h_img);
    x2 = fminf(fmaxf(x2, 0.f), w_img);
    y2 = fminf(fmaxf(y2, 0.f), h_img);
    float* o = selB + ((size_t)img * PRE + k) * 4;
    o[0] = x1; o[1] = y1; o[2] = x2; o[3] = y2;
  }
}

// ---------------- RPN NMS suppression-mask build ----------------
// grid (8 rowblocks, 4 j-splits, 2 img), 256 threads
__global__ __launch_bounds__(256) void nms_mask(const float* __restrict__ selB, u64* __restrict__ mask) {
  const int img = blockIdx.z;
  const int jr0 = blockIdx.y * 512;
  const int i = blockIdx.x * 256 + threadIdx.x;  // 0..2047
  __shared__ float bx[PRE][4];
  __shared__ float ar[PRE];
  const int tid = threadIdx.x;
  for (int l = tid; l < PRE * 4; l += 256) bx[l >> 2][l & 3] = selB[(size_t)img * PRE * 4 + l];
  __syncthreads();
  for (int l = tid; l < PRE; l += 256) ar[l] = (bx[l][2] - bx[l][0]) * (bx[l][3] - bx[l][1]);
  __syncthreads();
  float x1 = 0, y1 = 0, x2 = 0, y2 = 0, ai = 0;
  if (i < PRE) { x1 = bx[i][0]; y1 = bx[i][1]; x2 = bx[i][2]; y2 = bx[i][3]; ai = ar[i]; }
  u64 cur = 0;
  for (int j = jr0; j < jr0 + 512; ++j) {
    bool bit = false;
    if (i < PRE && j < PRE && j > i) {
      float ltx = fmaxf(x1, bx[j][0]);
      float lty = fmaxf(y1, bx[j][1]);
      float rbx = fminf(x2, bx[j][2]);
      float rby = fminf(y2, bx[j][3]);
      float iw = fmaxf(rbx - ltx, 0.f);
      float ih = fmaxf(rby - lty, 0.f);
      float inter = iw * ih;
      float iou = inter / (ai + ar[j] - inter + 1e-9f);
      bit = iou > RPN_T;
    }
    cur |= ((u64)bit) << (j & 63);
    if ((j & 63) == 63) {
      if (i < PRE) mask[((size_t)img * PRE + i) * 32 + (j >> 6)] = cur;
      cur = 0;
    }
  }
}

// ---------------- RPN NMS serial scan + keep-list + box gather ----------------
// grid 2, 64 threads (one wave)
__global__ __launch_bounds__(64) void rpn_scan(const u64* __restrict__ mask,
    const float* __restrict__ selB, float* __restrict__ pb) {
  const int img = blockIdx.x;
  const int lane = threadIdx.x;
  const u64* mrow = mask + (size_t)img * PRE * 32;
  u64 keep = 0;
  if (lane < 31) keep = ~0ULL;
  else if (lane == 31) keep = (1ULL << 16) - 1;  // 2000 = 31*64 + 16
  for (int c = 0; c < PRE; c += 8) {
    u64 m0 = 0, m1 = 0, m2 = 0, m3 = 0, m4 = 0, m5 = 0, m6 = 0, m7 = 0;
    if (lane < 32) {
      const u64* p = mrow + (size_t)c * 32 + lane;
      m0 = p[0];   m1 = p[32];  m2 = p[64];  m3 = p[96];
      m4 = p[128]; m5 = p[160]; m6 = p[192]; m7 = p[224];
    }
#pragma unroll
    for (int k = 0; k < 8; ++k) {
      int i = c + k;
      u64 kw = __shfl(keep, i >> 6);
      if ((kw >> (i & 63)) & 1ULL) {
        u64 mm = (k == 0) ? m0 : (k == 1) ? m1 : (k == 2) ? m2 : (k == 3) ? m3
               : (k == 4) ? m4 : (k == 5) ? m5 : (k == 6) ? m6 : m7;
        keep &= ~mm;
      }
    }
  }
  __shared__ u64 kws[32];
  __shared__ int rows[POST];
  if (lane < 32) kws[lane] = keep;
  __syncthreads();
  if (lane == 0) {
    int cnt = 0;
    for (int w = 0; w < 32 && cnt < POST; ++w) {
      u64 kv = kws[w];
      while (kv && cnt < POST) {
        int b = __ffsll((unsigned long long)kv) - 1;
        int i = w * 64 + b;
        if (i < PRE) rows[cnt++] = i;
        kv &= kv - 1;
      }
    }
    for (int w = 0; w < 32 && cnt < POST; ++w) {
      u64 kv = ~kws[w];
      while (kv && cnt < POST) {
        int b = __ffsll((unsigned long long)kv) - 1;
        int i = w * 64 + b;
        if (i < PRE) rows[cnt++] = i;
        kv &= kv - 1;
      }
    }
  }
  __syncthreads();
  for (int k = lane; k < POST; k += 64) {
    int row = rows[k];
    const float* s = selB + ((size_t)img * PRE + row) * 4;
    float* d = pb + ((size_t)img * POST + k) * 4;
    d[0] = s[0]; d[1] = s[1]; d[2] = s[2]; d[3] = s[3];
  }
}

// ---------------- RoI align (7x7, mean) on NHWC feat ----------------
// grid 600 (one box), 256 threads (4 channels each)
__global__ __launch_bounds__(256) void roi_kernel(const float* __restrict__ featT,
    const float* __restrict__ pb, float* __restrict__ pooled) {
  const int box = blockIdx.x;
  const int img = box / POST;
  const int tid = threadIdx.x;
  const float scl = 0.0625f;
  float x1 = pb[box * 4 + 0] * scl, y1 = pb[box * 4 + 1] * scl;
  float x2 = pb[box * 4 + 2] * scl, y2 = pb[box * 4 + 3] * scl;
  const float* fb = featT + (size_t)img * CHW * CC;
  const int c0 = tid * 4;
  float a0 = 0, a1 = 0, a2 = 0, a3 = 0;
  for (int by = 0; by < 7; ++by) {
    float gy = ((float)by + 0.5f) / 7.0f;
    float ys = y1 + gy * (y2 - y1) - 0.5f;
    float yf = floorf(ys);
    float ly = ys - yf;
    int y0i = (int)yf;
    y0i = y0i < 0 ? 0 : (y0i > CH - 1 ? CH - 1 : y0i);
    int y1i = (y0i + 1 > CH - 1) ? CH - 1 : y0i + 1;
    for (int bx2 = 0; bx2 < 7; ++bx2) {
      float gx = ((float)bx2 + 0.5f) / 7.0f;
      float xs = x1 + gx * (x2 - x1) - 0.5f;
      float xf = floorf(xs);
      float lx = xs - xf;
      int x0i = (int)xf;
      x0i = x0i < 0 ? 0 : (x0i > CW - 1 ? CW - 1 : x0i);
      int x1i = (x0i + 1 > CW - 1) ? CW - 1 : x0i + 1;
      float w00 = (1.f - ly) * (1.f - lx), w01 = (1.f - ly) * lx;
      float w10 = ly * (1.f - lx), w11 = ly * lx;
      const float4 v00 = *reinterpret_cast<const float4*>(fb + ((size_t)y0i * CW + x0i) * CC + c0);
      const float4 v01 = *reinterpret_cast<const float4*>(fb + ((size_t)y0i * CW + x1i) * CC + c0);
      const float4 v10 = *reinterpret_cast<const float4*>(fb + ((size_t)y1i * CW + x0i) * CC + c0);
      const float4 v11 = *reinterpret_cast<const float4*>(fb + ((size_t)y1i * CW + x1i) * CC + c0);
      a0 += w00 * v00.x + w01 * v01.x + w10 * v10.x + w11 * v11.x;
      a1 += w00 * v00.y + w01 * v01.y + w10 * v10.y + w11 * v11.y;
      a2 += w00 * v00.z + w01 * v01.z + w10 * v10.z + w11 * v11.z;
      a3 += w00 * v00.w + w01 * v01.w + w10 * v10.w + w11 * v11.w;
    }
  }
  float* o = pooled + (size_t)box * CC + c0;
  o[0] = a0 / 49.f; o[1] = a1 / 49.f; o[2] = a2 / 49.f; o[3] = a3 / 49.f;
}

// ---------------- FC: logits[600][1605] = pooled @ [cls_w;box_w]^T + bias ----------------
__global__ __launch_bounds__(256) void fc_gemm(const float* __restrict__ pooled,
    const float* __restrict__ clsw, const float* __restrict__ clsb,
    const float* __restrict__ boxw, const float* __restrict__ boxb,
    float* __restrict__ logits) {
  __shared__ float As[32][65];
  __shared__ float Bs[32][65];
  const int m0 = blockIdx.x * 64;
  const int n0 = blockIdx.y * 64;
  const int tid = threadIdx.x;
  const int tm = tid & 15, tn = tid >> 4;
  float acc[4][4] = {};
  for (int kc = 0; kc < CC; kc += 32) {
    __syncthreads();
    for (int l = tid; l < 2048; l += 256) {
      int mm = l >> 5, kk = l & 31;
      int mA = m0 + mm;
      As[kk][mm] = (mA < CB * POST) ? pooled[(size_t)mA * CC + kc + kk] : 0.f;
      int nB = n0 + mm;
      float bv = 0.f;
      if (nB < 1601) bv = clsw[(size_t)nB * CC + kc + kk];
      else if (nB < GN) bv = boxw[(size_t)(nB - 1601) * CC + kc + kk];
      Bs[kk][mm] = bv;
    }
    __syncthreads();
#pragma unroll
    for (int kk = 0; kk < 32; ++kk) {
      float a[4], b[4];
#pragma unroll
      for (int ii = 0; ii < 4; ++ii) a[ii] = As[kk][tm * 4 + ii];
#pragma unroll
      for (int jj = 0; jj < 4; ++jj) b[jj] = Bs[kk][tn * 4 + jj];
#pragma unroll
      for (int ii = 0; ii < 4; ++ii)
#pragma unroll
        for (int jj = 0; jj < 4; ++jj)
          acc[ii][jj] = fmaf(a[ii], b[jj], acc[ii][jj]);
    }
  }
  for (int ii = 0; ii < 4; ++ii) {
    int mA = m0 + tm * 4 + ii;
    if (mA >= CB * POST) continue;
    for (int jj = 0; jj < 4; ++jj) {
      int nB = n0 + tn * 4 + jj;
      if (nB >= GN) continue;
      float bias = (nB < 1601) ? clsb[nB] : boxb[nB - 1601];
      logits[(size_t)mA * GN + nB] = acc[ii][jj] + bias;
    }
  }
}

// ---------------- softmax (1601) -> cls_probs (1600), msc, det box decode + clip, score gate ----
__global__ __launch_bounds__(256) void softmax_det(
    const float* __restrict__ logits, const float* __restrict__ pb,
    const int* __restrict__ isz, float* __restrict__ clsp,
    float* __restrict__ detbox, float* __restrict__ dets) {
  const int row = blockIdx.x;
  const int tid = threadIdx.x;
  const float* lr = logits + (size_t)row * GN;
  __shared__ float red[256];
  float m = -INFINITY;
  for (int c = tid; c < 1600; c += 256) m = fmaxf(m, lr[c]);
  red[tid] = m;
  __syncthreads();
  for (int s = 128; s > 0; s >>= 1) {
    if (tid < s) red[tid] = fmaxf(red[tid], red[tid + s]);
    __syncthreads();
  }
  const float m1600 = red[0];
  __syncthreads();
  const float mall = fmaxf(m1600, lr[1600]);
  float sum = 0.f;
  for (int c = tid; c < 1601; c += 256) sum += expf(lr[c] - mall);
  red[tid] = sum;
  __syncthreads();
  for (int s = 128; s > 0; s >>= 1) {
    if (tid < s) red[tid] += red[tid + s];
    __syncthreads();
  }
  const float ssum = red[0];
  for (int c = tid; c < 1600; c += 256)
    clsp[(size_t)row * NCLS + c] = expf(lr[c] - mall) / ssum;
  if (tid == 0) {
    float msc = expf(m1600 - mall) / ssum;
    int img = row / POST;
    float hh = (float)isz[img * 2 + 0], ww = (float)isz[img * 2 + 1];
    float bx1 = pb[row * 4 + 0], by1 = pb[row * 4 + 1];
    float bx2 = pb[row * 4 + 2], by2 = pb[row * 4 + 3];
    float w = bx2 - bx1, h = by2 - by1;
    float cx = bx1 + 0.5f * w, cy = by1 + 0.5f * h;
    float d0 = lr[1601] / 10.0f, d1 = lr[1602] / 10.0f;
    float d2 = fminf(lr[1603] / 5.0f, CLIPLOG), d3 = fminf(lr[1604] / 5.0f, CLIPLOG);
    float pcx = d0 * w + cx, pcy = d1 * h + cy;
    float pw = expf(d2) * w, ph = expf(d3) * h;
    float xx1 = pcx - 0.5f * pw, yy1 = pcy - 0.5f * ph;
    float xx2 = pcx + 0.5f * pw, yy2 = pcy + 0.5f * ph;
    xx1 = fminf(fmaxf(xx1, 0.f), ww);
    xx2 = fminf(fmaxf(xx2, 0.f), ww);
    yy1 = fminf(fmaxf(yy1, 0.f), hh);
    yy2 = fminf(fmaxf(yy2, 0.f), hh);
    detbox[row * 4 + 0] = xx1; detbox[row * 4 + 1] = yy1;
    detbox[row * 4 + 2] = xx2; detbox[row * 4 + 3] = yy2;
    dets[row] = msc > SCORE_T_ ? msc : -INFINITY;
  }
}

// ---------------- det NMS (sort 300 + mask + scan + top_k-exact selection) -> global rows -------
// Selection replicates top_k(where(keep, s, -inf), 100):
//   Class A: kept AND finite score, ascending sorted position (s sorted desc);
//   Class B: everything else (suppressed OR kept-with--inf), ascending position.
__global__ __launch_bounds__(512) void det_nms(const float* __restrict__ dets,
    const float* __restrict__ detbox, int* __restrict__ ridx) {
  const int img = blockIdx.x;
  const int tid = threadIdx.x;
  __shared__ u64 arr[512];
  {
    u64 v = ~0ULL;
    if (tid < POST) {
      u32 key = fkey(dets[img * POST + tid]);
      v = ((u64)(~key) << 32) | (u32)tid;  // ascending = score desc, idx asc (stable argsort(-s))
    }
    arr[tid] = v;
  }
  __syncthreads();
  for (int kk = 2; kk <= 512; kk <<= 1) {
    for (int j = kk >> 1; j > 0; j >>= 1) {
      int ixj = tid ^ j;
      if (ixj > tid) {
        u64 a = arr[tid], bb = arr[ixj];
        bool up = ((tid & kk) == 0);
        if ((a > bb) == up) { arr[tid] = bb; arr[ixj] = a; }
      }
      __syncthreads();
    }
  }
  __shared__ float bx[POST][4];
  __shared__ float ar2[POST];
  __shared__ int ord[POST];
  __shared__ unsigned char fin[POST];
  if (tid < POST) {
    int o = (int)(u32)arr[tid];
    ord[tid] = o;
    fin[tid] = (dets[img * POST + o] != -INFINITY) ? 1 : 0;
    const float* s = detbox + ((size_t)img * POST + o) * 4;
    bx[tid][0] = s[0]; bx[tid][1] = s[1]; bx[tid][2] = s[2]; bx[tid][3] = s[3];
    ar2[tid] = (s[2] - s[0]) * (s[3] - s[1]);
  }
  __syncthreads();
  __shared__ u64 sm[POST][5];
  if (tid < POST) {
    const int i = tid;
    float x1 = bx[i][0], y1 = bx[i][1], x2 = bx[i][2], y2 = bx[i][3], ai = ar2[i];
    for (int w = 0; w < 5; ++w) {
      u64 cur = 0;
      for (int b = 0; b < 64; ++b) {
        int j = w * 64 + b;
        if (j < POST && j > i) {
          float ltx = fmaxf(x1, bx[j][0]);
          float lty = fmaxf(y1, bx[j][1]);
          float rbx = fminf(x2, bx[j][2]);
          float rby = fminf(y2, bx[j][3]);
          float iw = fmaxf(rbx - ltx, 0.f);
          float ih = fmaxf(rby - lty, 0.f);
          float inter = iw * ih;
          float iou = inter / (ai + ar2[j] - inter + 1e-9f);
          if (iou > DET_T) cur |= 1ULL << b;
        }
      }
      sm[i][w] = cur;
    }
  }
  __syncthreads();
  __shared__ u64 kws[5];
  if (tid < 64) {
    u64 keep = 0;
    if (tid < 4) keep = ~0ULL;
    else if (tid == 4) keep = (1ULL << 44) - 1;  // 300 = 4*64 + 44
    for (int i = 0; i < POST; ++i) {
      u64 kw = __shfl(keep, i >> 6);
      if ((kw >> (i & 63)) & 1ULL) {
        if (tid < 5) keep &= ~sm[i][tid];
      }
    }
    if (tid < 5) kws[tid] = keep;
  }
  __syncthreads();
  __shared__ int sel[NDET];
  if (tid == 0) {
    int cnt = 0;
    for (int i = 0; i < POST && cnt < NDET; ++i) {
      bool kept = (kws[i >> 6] >> (i & 63)) & 1ULL;
      if (kept && fin[i]) sel[cnt++] = i;   // Class A: kept with finite score
    }
    for (int i = 0; i < POST && cnt < NDET; ++i) {
      bool kept = (kws[i >> 6] >> (i & 63)) & 1ULL;
      if (!(kept && fin[i])) sel[cnt++] = i;  // Class B: all -inf entries in top_k
    }
  }
  __syncthreads();
  if (tid < NDET) ridx[img * NDET + tid] = img * POST + ord[sel[tid]];
}

// ---------------- final gather into d_out: [pooled 200x1024][boxes 200x4][probs 200x1600] -------
__global__ __launch_bounds__(256) void gather_out(const int* __restrict__ ridx,
    const float* __restrict__ pooled, const float* __restrict__ pb,
    const float* __restrict__ clsp, float* __restrict__ out) {
  const int n = blockIdx.x;
  const int tid = threadIdx.x;
  const int row = ridx[n];
  for (int c = tid; c < CC; c += 256)
    out[(size_t)n * CC + c] = pooled[(size_t)row * CC + c];
  if (tid < 4)
    out[204800 + n * 4 + tid] = pb[row * 4 + tid];
  for (int c = tid; c < NCLS; c += 256)
    out[205600 + (size_t)n * NCLS + c] = clsp[(size_t)row * NCLS + c];
}

extern "C" void kernel_launch(void* const* d_in, const int* in_sizes, int n_in,
                              void* d_out, int out_size, void* d_ws, size_t ws_size,
                              hipStream_t stream) {
  (void)in_sizes; (void)n_in; (void)out_size;
  const int* isz = (const int*)d_in[1];
  const float* feat = (const float*)d_in[2];
  const float* convw = (const float*)d_in[3];
  const float* convb = (const float*)d_in[4];
  const float* objw = (const float*)d_in[5];
  const float* objb = (const float*)d_in[6];
  const float* dltw = (const float*)d_in[7];
  const float* dltb = (const float*)d_in[8];
  const float* clsw = (const float*)d_in[9];
  const float* clsb = (const float*)d_in[10];
  const float* boxw = (const float*)d_in[11];
  const float* boxb = (const float*)d_in[12];
  float* out = (float*)d_out;

  char* wsb = (char*)d_ws;
  size_t off = 0;
  auto alloc = [&](size_t bytes) -> void* {
    void* p = wsb + off;
    off = (off + bytes + 255) & ~(size_t)255;
    return p;
  };
  float* t = (float*)alloc((size_t)CB * CHW * CC * 4);      // conv partial ks=0 / t / later featT
  float* scores = (float*)alloc((size_t)CB * NANCH * 4);
  float* deltas = (float*)alloc((size_t)CB * NANCH * 4 * 4);
  float* selB = (float*)alloc((size_t)CB * PRE * 4 * 4);
  u64* mask = (u64*)alloc((size_t)CB * PRE * 32 * 8);
  float* pb = (float*)alloc((size_t)CB * POST * 4 * 4);
  float* pooled = (float*)alloc((size_t)CB * POST * CC * 4);
  float* logits = (float*)alloc((size_t)CB * POST * GN * 4);
  float* clsp = (float*)alloc((size_t)CB * POST * NCLS * 4);
  float* detbox = (float*)alloc((size_t)CB * POST * 4 * 4);
  float* dets = (float*)alloc((size_t)CB * POST * 4);
  int* ridx = (int*)alloc((size_t)CB * NDET * 4);
  if (off > ws_size) return;  // base layout must fit

  // K-split partial buffer allocated LAST: fall back to single-split if ws is tight
  size_t base_off = off;
  float* p1 = (float*)alloc((size_t)CB * CHW * CC * 4);
  int nks = 2, klen = 512;
  if (off > ws_size) { nks = 1; klen = 1024; p1 = t; off = base_off; }

  conv3x3p<<<dim3(8 * nks, CH, CB), 256, 0, stream>>>(feat, convw, t, p1, klen);
  reduce_br<<<dim3((CB * CHW * CC) / 1024), 256, 0, stream>>>(p1, convb, t, nks - 1);
  heads<<<dim3(CB * CHW / 16), 256, 0, stream>>>(t, objw, objb, dltw, dltb, scores, deltas);
  transp<<<dim3((CHW + 31) / 32, CC / 32, CB), dim3(32, 8), 0, stream>>>(feat, t);  // t := featT
  topk_props<<<dim3(CB), 1024, 0, stream>>>(scores, deltas, isz, selB);
  nms_mask<<<dim3(8, 4, CB), 256, 0, stream>>>(selB, mask);
  rpn_scan<<<dim3(CB), 64, 0, stream>>>(mask, selB, pb);
  roi_kernel<<<dim3(CB * POST), 256, 0, stream>>>(t, pb, pooled);
  fc_gemm<<<dim3(10, 26), 256, 0, stream>>>(pooled, clsw, clsb, boxw, boxb, logits);
  softmax_det<<<dim3(CB * POST), 256, 0, stream>>>(logits, pb, isz, clsp, detbox, dets);
  det_nms<<<dim3(CB), 512, 0, stream>>>(dets, detbox, ridx);
  gather_out<<<dim3(CB * NDET), 256, 0, stream>>>(ridx, pooled, pb, clsp, out);
}

// Round 5
// 5577.194 us; speedup vs baseline: 1.2936x; 1.2936x over previous
//
#include <hip/hip_runtime.h>
#include <cmath>

typedef unsigned long long u64;
typedef unsigned int u32;

constexpr int CB = 2;
constexpr int CC = 1024;
constexpr int CH = 50;
constexpr int CW = 76;
constexpr int CHW = CH * CW;        // 3800
constexpr int CA = 15;
constexpr int NANCH = CHW * CA;     // 57000
constexpr int PRE = 2000;
constexpr int POST = 300;
constexpr int NDET = 100;
constexpr int NCLS = 1600;
constexpr int GN = 1605;            // 1601 cls logits + 4 box deltas
constexpr float RPN_T = 0.7f;
constexpr float DET_T = 0.5f;
constexpr float SCORE_T_ = 0.05f;
constexpr float CLIPLOG = 4.135166556742356f;

__device__ __forceinline__ u32 fkey(float f) {
  u32 u = __float_as_uint(f);
  return (u & 0x80000000u) ? ~u : (u | 0x80000000u);
}

// ---------------- RPN 3x3 conv partials (no bias/relu), pixel-major ----------------
// v5: v1 skeleton (1 oc/thread, 64 oc/block) + 8-ic steps fully unrolled (all LDS at
// imm offsets, no addr VALU) + per-wave 16B-aligned input slices read as ds_read_b128
// broadcasts + 31KB LDS -> 5 blocks/CU. Grid (16 octiles * nks, 50 y, 2 b), 256 thr.
// Block computes ic in [ks*klen, (ks+1)*klen) -> partial buffer pp[ks].
__global__ __launch_bounds__(256, 5) void conv3x3p(
    const float* __restrict__ feat, const float* __restrict__ wgt,
    float* __restrict__ p0, float* __restrict__ p1,
    float* __restrict__ p2, float* __restrict__ p3, int klen) {
  __shared__ float wl[64][73];      // [oc][ic*9+tap]; odd stride 73 -> 2-way (free) reads
  __shared__ float inl[8][3][128];  // [ic][ky][wave*32 + f], f<24 staged; 16B-aligned slices
  const int bx = blockIdx.x;
  const int octile = bx & 15, ks = bx >> 4;
  const int y = blockIdx.y, b = blockIdx.z;
  const int oc0 = octile * 64;
  const int tid = threadIdx.x;
  const int lane = tid & 63;
  const int wid = tid >> 6;          // wave id = pixel group (4 x 19 px)
  const int x0 = wid * 19;
  float acc[19];
#pragma unroll
  for (int p = 0; p < 19; ++p) acc[p] = 0.f;
  const float* fb = feat + (size_t)b * CC * CHW;
  const int icbeg = ks * klen;
  for (int ic0 = icbeg; ic0 < icbeg + klen; ic0 += 8) {
    __syncthreads();
    // stage weights: 64 oc x 72 taps (8 ic x 9), coalesced global reads
    for (int l = tid; l < 64 * 72; l += 256) {
      int o = l / 72, k = l - o * 72;
      wl[o][k] = wgt[(size_t)(oc0 + o) * 9216 + ic0 * 9 + k];
    }
    // stage inputs: per-wave slices, slot f of wave w = global x (19w - 1 + f), f<24
    for (int l = tid; l < 8 * 3 * 128; l += 256) {
      int k = l & 127;
      int f = k & 31, w = k >> 5;
      if (f < 24) {
        int icr = l >> 7;            // ic*3 + r, 0..23
        int ic = icr / 3;
        int r = icr - ic * 3;
        int yy = y + r - 1;
        int x = 19 * w - 1 + f;
        float v = 0.f;
        if (yy >= 0 && yy < CH && (unsigned)x < (unsigned)CW)
          v = fb[(size_t)(ic0 + ic) * CHW + yy * CW + x];
        inl[icr >> 5][0][0] = 0.f;   // dummy never executed path guard (optimized out)
        inl[ic][r][k] = v;
      }
    }
    __syncthreads();
#pragma unroll
    for (int ic = 0; ic < 8; ++ic) {
#pragma unroll
      for (int ky = 0; ky < 3; ++ky) {
        float inv[24];
        const float* ib = &inl[ic][ky][wid * 32];
#pragma unroll
        for (int q = 0; q < 6; ++q) {
          float4 v4 = *reinterpret_cast<const float4*>(ib + q * 4);  // b128 broadcast, imm offset
          inv[q * 4 + 0] = v4.x; inv[q * 4 + 1] = v4.y;
          inv[q * 4 + 2] = v4.z; inv[q * 4 + 3] = v4.w;
        }
        const int c = ic * 9 + ky * 3;
        const float w0 = wl[lane][c], w1 = wl[lane][c + 1], w2 = wl[lane][c + 2];
#pragma unroll
        for (int p = 0; p < 19; ++p) {
          acc[p] = fmaf(w0, inv[p], acc[p]);
          acc[p] = fmaf(w1, inv[p + 1], acc[p]);
          acc[p] = fmaf(w2, inv[p + 2], acc[p]);
        }
      }
    }
  }
  float* pp = (ks == 0) ? p0 : (ks == 1) ? p1 : (ks == 2) ? p2 : p3;
#pragma unroll
  for (int p = 0; p < 19; ++p) {
    int x = x0 + p;
    pp[((size_t)b * CHW + y * CW + x) * CC + oc0 + lane] = acc[p];
  }
}

// ---------------- t = relu(p0 + p1 + p2 + p3 + bias), in-place on t(=p0) ----------------
__global__ __launch_bounds__(256) void reduce_br(
    const float* __restrict__ p1, const float* __restrict__ p2,
    const float* __restrict__ p3, const float* __restrict__ bias,
    float* __restrict__ t, int nparts) {
  size_t i = ((size_t)blockIdx.x * 256 + threadIdx.x) * 4;
  float4 a = *reinterpret_cast<const float4*>(t + i);
  int oc = (int)(i & (CC - 1));
  const float4 bv = *reinterpret_cast<const float4*>(bias + oc);
  if (nparts > 1) {
    const float4 c = *reinterpret_cast<const float4*>(p1 + i);
    a.x += c.x; a.y += c.y; a.z += c.z; a.w += c.w;
  }
  if (nparts > 2) {
    const float4 c = *reinterpret_cast<const float4*>(p2 + i);
    a.x += c.x; a.y += c.y; a.z += c.z; a.w += c.w;
  }
  if (nparts > 3) {
    const float4 c = *reinterpret_cast<const float4*>(p3 + i);
    a.x += c.x; a.y += c.y; a.z += c.z; a.w += c.w;
  }
  a.x = fmaxf(a.x + bv.x, 0.f); a.y = fmaxf(a.y + bv.y, 0.f);
  a.z = fmaxf(a.z + bv.z, 0.f); a.w = fmaxf(a.w + bv.w, 0.f);
  *reinterpret_cast<float4*>(t + i) = a;
}

// ---------------- obj (15) & delta (60) 1x1 heads ----------------
// grid 475 (16 px each), 256 threads = 64 o-lanes x 4 pixel groups
__global__ __launch_bounds__(256) void heads(
    const float* __restrict__ t,
    const float* __restrict__ ow, const float* __restrict__ ob,
    const float* __restrict__ dw, const float* __restrict__ db,
    float* __restrict__ scores, float* __restrict__ deltas) {
  __shared__ float tl[16][64];
  __shared__ float wl[64][81];  // [k][o] o<75
  const int tid = threadIdx.x;
  const int px0 = blockIdx.x * 16;
  const int lo = tid & 63, pg = tid >> 6;
  float accA[4] = {0, 0, 0, 0}, accB[4] = {0, 0, 0, 0};
  for (int kc = 0; kc < CC; kc += 64) {
    __syncthreads();
    for (int l = tid; l < 16 * 64; l += 256) {
      int p = l >> 6, k = l & 63;
      tl[p][k] = t[(size_t)(px0 + p) * CC + kc + k];
    }
    for (int l = tid; l < 75 * 64; l += 256) {
      int o = l >> 6, k = l & 63;
      wl[k][o] = (o < 15) ? ow[o * CC + kc + k] : dw[(o - 15) * CC + kc + k];
    }
    __syncthreads();
#pragma unroll 8
    for (int k = 0; k < 64; ++k) {
      float w1 = wl[k][lo];
      float w2 = (lo < 11) ? wl[k][64 + lo] : 0.f;
#pragma unroll
      for (int p = 0; p < 4; ++p) {
        float tv = tl[pg * 4 + p][k];
        accA[p] = fmaf(w1, tv, accA[p]);
        accB[p] = fmaf(w2, tv, accB[p]);
      }
    }
  }
#pragma unroll
  for (int p = 0; p < 4; ++p) {
    int px = px0 + pg * 4 + p;
    int b = px / CHW, pix = px - b * CHW;
    {
      int o = lo;
      float v = accA[p];
      if (o < 15) {
        scores[(size_t)b * NANCH + (size_t)pix * CA + o] = v + ob[o];
      } else {
        int oo = o - 15;
        deltas[((size_t)b * NANCH + (size_t)pix * CA + (oo >> 2)) * 4 + (oo & 3)] = v + db[oo];
      }
    }
    if (lo < 11) {
      int oo = 64 + lo - 15;  // 49..59
      deltas[((size_t)b * NANCH + (size_t)pix * CA + (oo >> 2)) * 4 + (oo & 3)] = accB[p] + db[oo];
    }
  }
}

// ---------------- feat NCHW -> NHWC transpose (for coalesced roi_align) ----------------
__global__ __launch_bounds__(256) void transp(const float* __restrict__ in, float* __restrict__ outT) {
  __shared__ float tile[32][33];
  int b = blockIdx.z;
  int p0 = blockIdx.x * 32, c0 = blockIdx.y * 32;
  int tx = threadIdx.x, ty = threadIdx.y;
  for (int i = ty; i < 32; i += 8) {
    int p = p0 + tx;
    tile[i][tx] = (p < CHW) ? in[((size_t)b * CC + c0 + i) * CHW + p] : 0.f;
  }
  __syncthreads();
  for (int i = ty; i < 32; i += 8) {
    int p = p0 + i;
    if (p < CHW) outT[((size_t)b * CHW + p) * CC + c0 + tx] = tile[tx][i];
  }
}

// ---------------- exact top-2000 (radix threshold + bitonic sort) + proposal decode + clip ------
// grid 2 (per image), 1024 threads
__global__ __launch_bounds__(1024) void topk_props(
    const float* __restrict__ scores, const float* __restrict__ deltas,
    const int* __restrict__ isz, float* __restrict__ selB) {
  const int img = blockIdx.x;
  const int tid = threadIdx.x;
  const float* sc = scores + (size_t)img * NANCH;
  __shared__ u32 hist[256];
  __shared__ u32 s_prefix, s_need, s_cnt;
  __shared__ u64 arr[4096];

  u32 prefix = 0, need = PRE;
  for (int byte = 3; byte >= 0; --byte) {
    if (tid < 256) hist[tid] = 0;
    __syncthreads();
    for (int i = tid; i < NANCH; i += 1024) {
      u32 key = fkey(sc[i]);
      bool ok = (byte == 3) || ((key >> (8 * byte + 8)) == prefix);
      if (ok) atomicAdd(&hist[(key >> (8 * byte)) & 255], 1u);
    }
    __syncthreads();
    if (tid == 0) {
      u32 cum = 0;
      int bin;
      for (bin = 255; bin >= 0; --bin) {
        cum += hist[bin];
        if (cum >= need) break;
      }
      s_need = need - (cum - hist[bin]);
      s_prefix = (prefix << 8) | (u32)bin;
    }
    __syncthreads();
    prefix = s_prefix;
    need = s_need;
    __syncthreads();
  }
  const u32 T = prefix;  // count(key>T) < PRE <= count(key>=T)
  if (tid == 0) s_cnt = 0;
  __syncthreads();
  for (int i = tid; i < NANCH; i += 1024) {
    u32 key = fkey(sc[i]);
    if (key >= T) {
      u32 p = atomicAdd(&s_cnt, 1u);
      if (p < 4096) arr[p] = ((u64)(~key) << 32) | (u32)i;  // ascending rank = score desc, idx asc
    }
  }
  __syncthreads();
  int n = (int)(s_cnt < 4096u ? s_cnt : 4096u);
  for (int i = tid; i < 4096; i += 1024)
    if (i >= n) arr[i] = ~0ULL;
  __syncthreads();
  for (int kk = 2; kk <= 4096; kk <<= 1) {
    for (int j = kk >> 1; j > 0; j >>= 1) {
      for (int i = tid; i < 4096; i += 1024) {
        int ixj = i ^ j;
        if (ixj > i) {
          u64 a = arr[i], bb = arr[ixj];
          bool up = ((i & kk) == 0);
          if ((a > bb) == up) { arr[i] = bb; arr[ixj] = a; }
        }
      }
      __syncthreads();
    }
  }
  // decode anchor + apply deltas + clip for the top PRE (sorted)
  const float h_img = (float)isz[img * 2 + 0];
  const float w_img = (float)isz[img * 2 + 1];
  const float* dl = deltas + (size_t)img * NANCH * 4;
  for (int k = tid; k < PRE; k += 1024) {
    u32 idx = (u32)arr[k];
    int aa = (int)(idx % 15u);
    int p = (int)(idx / 15u);
    int xx = p % CW, yy = p / CW;
    double szd = 32.0 * (double)(1 << (aa / 3));
    double rr = 0.5 * (double)(1 << (aa % 3));
    double wd = szd * sqrt(1.0 / rr);
    double hd = wd * rr;
    float ax1 = (float)(xx * 16) + (float)(-wd * 0.5);
    float ax2 = (float)(xx * 16) + (float)(wd * 0.5);
    float ay1 = (float)(yy * 16) + (float)(-hd * 0.5);
    float ay2 = (float)(yy * 16) + (float)(hd * 0.5);
    float aw = ax2 - ax1, ah = ay2 - ay1;
    float cx = ax1 + 0.5f * aw, cy = ay1 + 0.5f * ah;
    float d0 = dl[(size_t)idx * 4 + 0], d1 = dl[(size_t)idx * 4 + 1];
    float d2 = dl[(size_t)idx * 4 + 2], d3 = dl[(size_t)idx * 4 + 3];
    float dwv = fminf(d2, CLIPLOG), dhv = fminf(d3, CLIPLOG);
    float pcx = d0 * aw + cx, pcy = d1 * ah + cy;
    float pw = expf(dwv) * aw, ph = expf(dhv) * ah;
    float x1 = pcx - 0.5f * pw, y1 = pcy - 0.5f * ph;
    float x2 = pcx + 0.5f * pw, y2 = pcy + 0.5f * ph;
    x1 = fminf(fmaxf(x1, 0.f), w_img);
    y1 = fminf(fmaxf(y1, 0.f), h_img);
    x2 = fminf(fmaxf(x2, 0.f), w_img);
    y2 = fminf(fmaxf(y2, 0.f), h_img);
    float* o = selB + ((size_t)img * PRE + k) * 4;
    o[0] = x1; o[1] = y1; o[2] = x2; o[3] = y2;
  }
}

// ---------------- RPN NMS suppression-mask build ----------------
// grid (8 rowblocks, 4 j-splits, 2 img), 256 threads
__global__ __launch_bounds__(256) void nms_mask(const float* __restrict__ selB, u64* __restrict__ mask) {
  const int img = blockIdx.z;
  const int jr0 = blockIdx.y * 512;
  const int i = blockIdx.x * 256 + threadIdx.x;  // 0..2047
  __shared__ float bx[PRE][4];
  __shared__ float ar[PRE];
  const int tid = threadIdx.x;
  for (int l = tid; l < PRE * 4; l += 256) bx[l >> 2][l & 3] = selB[(size_t)img * PRE * 4 + l];
  __syncthreads();
  for (int l = tid; l < PRE; l += 256) ar[l] = (bx[l][2] - bx[l][0]) * (bx[l][3] - bx[l][1]);
  __syncthreads();
  float x1 = 0, y1 = 0, x2 = 0, y2 = 0, ai = 0;
  if (i < PRE) { x1 = bx[i][0]; y1 = bx[i][1]; x2 = bx[i][2]; y2 = bx[i][3]; ai = ar[i]; }
  u64 cur = 0;
  for (int j = jr0; j < jr0 + 512; ++j) {
    bool bit = false;
    if (i < PRE && j < PRE && j > i) {
      float ltx = fmaxf(x1, bx[j][0]);
      float lty = fmaxf(y1, bx[j][1]);
      float rbx = fminf(x2, bx[j][2]);
      float rby = fminf(y2, bx[j][3]);
      float iw = fmaxf(rbx - ltx, 0.f);
      float ih = fmaxf(rby - lty, 0.f);
      float inter = iw * ih;
      float iou = inter / (ai + ar[j] - inter + 1e-9f);
      bit = iou > RPN_T;
    }
    cur |= ((u64)bit) << (j & 63);
    if ((j & 63) == 63) {
      if (i < PRE) mask[((size_t)img * PRE + i) * 32 + (j >> 6)] = cur;
      cur = 0;
    }
  }
}

// ---------------- RPN NMS serial scan + keep-list + box gather ----------------
// grid 2, 64 threads (one wave)
__global__ __launch_bounds__(64) void rpn_scan(const u64* __restrict__ mask,
    const float* __restrict__ selB, float* __restrict__ pb) {
  const int img = blockIdx.x;
  const int lane = threadIdx.x;
  const u64* mrow = mask + (size_t)img * PRE * 32;
  u64 keep = 0;
  if (lane < 31) keep = ~0ULL;
  else if (lane == 31) keep = (1ULL << 16) - 1;  // 2000 = 31*64 + 16
  for (int c = 0; c < PRE; c += 8) {
    u64 m0 = 0, m1 = 0, m2 = 0, m3 = 0, m4 = 0, m5 = 0, m6 = 0, m7 = 0;
    if (lane < 32) {
      const u64* p = mrow + (size_t)c * 32 + lane;
      m0 = p[0];   m1 = p[32];  m2 = p[64];  m3 = p[96];
      m4 = p[128]; m5 = p[160]; m6 = p[192]; m7 = p[224];
    }
#pragma unroll
    for (int k = 0; k < 8; ++k) {
      int i = c + k;
      u64 kw = __shfl(keep, i >> 6);
      if ((kw >> (i & 63)) & 1ULL) {
        u64 mm = (k == 0) ? m0 : (k == 1) ? m1 : (k == 2) ? m2 : (k == 3) ? m3
               : (k == 4) ? m4 : (k == 5) ? m5 : (k == 6) ? m6 : m7;
        keep &= ~mm;
      }
    }
  }
  __shared__ u64 kws[32];
  __shared__ int rows[POST];
  if (lane < 32) kws[lane] = keep;
  __syncthreads();
  if (lane == 0) {
    int cnt = 0;
    for (int w = 0; w < 32 && cnt < POST; ++w) {
      u64 kv = kws[w];
      while (kv && cnt < POST) {
        int b = __ffsll((unsigned long long)kv) - 1;
        int i = w * 64 + b;
        if (i < PRE) rows[cnt++] = i;
        kv &= kv - 1;
      }
    }
    for (int w = 0; w < 32 && cnt < POST; ++w) {
      u64 kv = ~kws[w];
      while (kv && cnt < POST) {
        int b = __ffsll((unsigned long long)kv) - 1;
        int i = w * 64 + b;
        if (i < PRE) rows[cnt++] = i;
        kv &= kv - 1;
      }
    }
  }
  __syncthreads();
  for (int k = lane; k < POST; k += 64) {
    int row = rows[k];
    const float* s = selB + ((size_t)img * PRE + row) * 4;
    float* d = pb + ((size_t)img * POST + k) * 4;
    d[0] = s[0]; d[1] = s[1]; d[2] = s[2]; d[3] = s[3];
  }
}

// ---------------- RoI align (7x7, mean) on NHWC feat ----------------
// grid 600 (one box), 256 threads (4 channels each)
__global__ __launch_bounds__(256) void roi_kernel(const float* __restrict__ featT,
    const float* __restrict__ pb, float* __restrict__ pooled) {
  const int box = blockIdx.x;
  const int img = box / POST;
  const int tid = threadIdx.x;
  const float scl = 0.0625f;
  float x1 = pb[box * 4 + 0] * scl, y1 = pb[box * 4 + 1] * scl;
  float x2 = pb[box * 4 + 2] * scl, y2 = pb[box * 4 + 3] * scl;
  const float* fb = featT + (size_t)img * CHW * CC;
  const int c0 = tid * 4;
  float a0 = 0, a1 = 0, a2 = 0, a3 = 0;
  for (int by = 0; by < 7; ++by) {
    float gy = ((float)by + 0.5f) / 7.0f;
    float ys = y1 + gy * (y2 - y1) - 0.5f;
    float yf = floorf(ys);
    float ly = ys - yf;
    int y0i = (int)yf;
    y0i = y0i < 0 ? 0 : (y0i > CH - 1 ? CH - 1 : y0i);
    int y1i = (y0i + 1 > CH - 1) ? CH - 1 : y0i + 1;
    for (int bx2 = 0; bx2 < 7; ++bx2) {
      float gx = ((float)bx2 + 0.5f) / 7.0f;
      float xs = x1 + gx * (x2 - x1) - 0.5f;
      float xf = floorf(xs);
      float lx = xs - xf;
      int x0i = (int)xf;
      x0i = x0i < 0 ? 0 : (x0i > CW - 1 ? CW - 1 : x0i);
      int x1i = (x0i + 1 > CW - 1) ? CW - 1 : x0i + 1;
      float w00 = (1.f - ly) * (1.f - lx), w01 = (1.f - ly) * lx;
      float w10 = ly * (1.f - lx), w11 = ly * lx;
      const float4 v00 = *reinterpret_cast<const float4*>(fb + ((size_t)y0i * CW + x0i) * CC + c0);
      const float4 v01 = *reinterpret_cast<const float4*>(fb + ((size_t)y0i * CW + x1i) * CC + c0);
      const float4 v10 = *reinterpret_cast<const float4*>(fb + ((size_t)y1i * CW + x0i) * CC + c0);
      const float4 v11 = *reinterpret_cast<const float4*>(fb + ((size_t)y1i * CW + x1i) * CC + c0);
      a0 += w00 * v00.x + w01 * v01.x + w10 * v10.x + w11 * v11.x;
      a1 += w00 * v00.y + w01 * v01.y + w10 * v10.y + w11 * v11.y;
      a2 += w00 * v00.z + w01 * v01.z + w10 * v10.z + w11 * v11.z;
      a3 += w00 * v00.w + w01 * v01.w + w10 * v10.w + w11 * v11.w;
    }
  }
  float* o = pooled + (size_t)box * CC + c0;
  o[0] = a0 / 49.f; o[1] = a1 / 49.f; o[2] = a2 / 49.f; o[3] = a3 / 49.f;
}

// ---------------- FC: logits[600][1605] = pooled @ [cls_w;box_w]^T + bias ----------------
__global__ __launch_bounds__(256) void fc_gemm(const float* __restrict__ pooled,
    const float* __restrict__ clsw, const float* __restrict__ clsb,
    const float* __restrict__ boxw, const float* __restrict__ boxb,
    float* __restrict__ logits) {
  __shared__ float As[32][65];
  __shared__ float Bs[32][65];
  const int m0 = blockIdx.x * 64;
  const int n0 = blockIdx.y * 64;
  const int tid = threadIdx.x;
  const int tm = tid & 15, tn = tid >> 4;
  float acc[4][4] = {};
  for (int kc = 0; kc < CC; kc += 32) {
    __syncthreads();
    for (int l = tid; l < 2048; l += 256) {
      int mm = l >> 5, kk = l & 31;
      int mA = m0 + mm;
      As[kk][mm] = (mA < CB * POST) ? pooled[(size_t)mA * CC + kc + kk] : 0.f;
      int nB = n0 + mm;
      float bv = 0.f;
      if (nB < 1601) bv = clsw[(size_t)nB * CC + kc + kk];
      else if (nB < GN) bv = boxw[(size_t)(nB - 1601) * CC + kc + kk];
      Bs[kk][mm] = bv;
    }
    __syncthreads();
#pragma unroll
    for (int kk = 0; kk < 32; ++kk) {
      float a[4], b[4];
#pragma unroll
      for (int ii = 0; ii < 4; ++ii) a[ii] = As[kk][tm * 4 + ii];
#pragma unroll
      for (int jj = 0; jj < 4; ++jj) b[jj] = Bs[kk][tn * 4 + jj];
#pragma unroll
      for (int ii = 0; ii < 4; ++ii)
#pragma unroll
        for (int jj = 0; jj < 4; ++jj)
          acc[ii][jj] = fmaf(a[ii], b[jj], acc[ii][jj]);
    }
  }
  for (int ii = 0; ii < 4; ++ii) {
    int mA = m0 + tm * 4 + ii;
    if (mA >= CB * POST) continue;
    for (int jj = 0; jj < 4; ++jj) {
      int nB = n0 + tn * 4 + jj;
      if (nB >= GN) continue;
      float bias = (nB < 1601) ? clsb[nB] : boxb[nB - 1601];
      logits[(size_t)mA * GN + nB] = acc[ii][jj] + bias;
    }
  }
}

// ---------------- softmax (1601) -> cls_probs (1600), msc, det box decode + clip, score gate ----
__global__ __launch_bounds__(256) void softmax_det(
    const float* __restrict__ logits, const float* __restrict__ pb,
    const int* __restrict__ isz, float* __restrict__ clsp,
    float* __restrict__ detbox, float* __restrict__ dets) {
  const int row = blockIdx.x;
  const int tid = threadIdx.x;
  const float* lr = logits + (size_t)row * GN;
  __shared__ float red[256];
  float m = -INFINITY;
  for (int c = tid; c < 1600; c += 256) m = fmaxf(m, lr[c]);
  red[tid] = m;
  __syncthreads();
  for (int s = 128; s > 0; s >>= 1) {
    if (tid < s) red[tid] = fmaxf(red[tid], red[tid + s]);
    __syncthreads();
  }
  const float m1600 = red[0];
  __syncthreads();
  const float mall = fmaxf(m1600, lr[1600]);
  float sum = 0.f;
  for (int c = tid; c < 1601; c += 256) sum += expf(lr[c] - mall);
  red[tid] = sum;
  __syncthreads();
  for (int s = 128; s > 0; s >>= 1) {
    if (tid < s) red[tid] += red[tid + s];
    __syncthreads();
  }
  const float ssum = red[0];
  for (int c = tid; c < 1600; c += 256)
    clsp[(size_t)row * NCLS + c] = expf(lr[c] - mall) / ssum;
  if (tid == 0) {
    float msc = expf(m1600 - mall) / ssum;
    int img = row / POST;
    float hh = (float)isz[img * 2 + 0], ww = (float)isz[img * 2 + 1];
    float bx1 = pb[row * 4 + 0], by1 = pb[row * 4 + 1];
    float bx2 = pb[row * 4 + 2], by2 = pb[row * 4 + 3];
    float w = bx2 - bx1, h = by2 - by1;
    float cx = bx1 + 0.5f * w, cy = by1 + 0.5f * h;
    float d0 = lr[1601] / 10.0f, d1 = lr[1602] / 10.0f;
    float d2 = fminf(lr[1603] / 5.0f, CLIPLOG), d3 = fminf(lr[1604] / 5.0f, CLIPLOG);
    float pcx = d0 * w + cx, pcy = d1 * h + cy;
    float pw = expf(d2) * w, ph = expf(d3) * h;
    float xx1 = pcx - 0.5f * pw, yy1 = pcy - 0.5f * ph;
    float xx2 = pcx + 0.5f * pw, yy2 = pcy + 0.5f * ph;
    xx1 = fminf(fmaxf(xx1, 0.f), ww);
    xx2 = fminf(fmaxf(xx2, 0.f), ww);
    yy1 = fminf(fmaxf(yy1, 0.f), hh);
    yy2 = fminf(fmaxf(yy2, 0.f), hh);
    detbox[row * 4 + 0] = xx1; detbox[row * 4 + 1] = yy1;
    detbox[row * 4 + 2] = xx2; detbox[row * 4 + 3] = yy2;
    dets[row] = msc > SCORE_T_ ? msc : -INFINITY;
  }
}

// ---------------- det NMS (sort 300 + mask + scan + top_k-exact selection) -> global rows -------
// Selection replicates top_k(where(keep, s, -inf), 100):
//   Class A: kept AND finite score, ascending sorted position (s sorted desc);
//   Class B: everything else (suppressed OR kept-with--inf), ascending position.
__global__ __launch_bounds__(512) void det_nms(const float* __restrict__ dets,
    const float* __restrict__ detbox, int* __restrict__ ridx) {
  const int img = blockIdx.x;
  const int tid = threadIdx.x;
  __shared__ u64 arr[512];
  {
    u64 v = ~0ULL;
    if (tid < POST) {
      u32 key = fkey(dets[img * POST + tid]);
      v = ((u64)(~key) << 32) | (u32)tid;  // ascending = score desc, idx asc (stable argsort(-s))
    }
    arr[tid] = v;
  }
  __syncthreads();
  for (int kk = 2; kk <= 512; kk <<= 1) {
    for (int j = kk >> 1; j > 0; j >>= 1) {
      int ixj = tid ^ j;
      if (ixj > tid) {
        u64 a = arr[tid], bb = arr[ixj];
        bool up = ((tid & kk) == 0);
        if ((a > bb) == up) { arr[tid] = bb; arr[ixj] = a; }
      }
      __syncthreads();
    }
  }
  __shared__ float bx[POST][4];
  __shared__ float ar2[POST];
  __shared__ int ord[POST];
  __shared__ unsigned char fin[POST];
  if (tid < POST) {
    int o = (int)(u32)arr[tid];
    ord[tid] = o;
    fin[tid] = (dets[img * POST + o] != -INFINITY) ? 1 : 0;
    const float* s = detbox + ((size_t)img * POST + o) * 4;
    bx[tid][0] = s[0]; bx[tid][1] = s[1]; bx[tid][2] = s[2]; bx[tid][3] = s[3];
    ar2[tid] = (s[2] - s[0]) * (s[3] - s[1]);
  }
  __syncthreads();
  __shared__ u64 sm[POST][5];
  if (tid < POST) {
    const int i = tid;
    float x1 = bx[i][0], y1 = bx[i][1], x2 = bx[i][2], y2 = bx[i][3], ai = ar2[i];
    for (int w = 0; w < 5; ++w) {
      u64 cur = 0;
      for (int b = 0; b < 64; ++b) {
        int j = w * 64 + b;
        if (j < POST && j > i) {
          float ltx = fmaxf(x1, bx[j][0]);
          float lty = fmaxf(y1, bx[j][1]);
          float rbx = fminf(x2, bx[j][2]);
          float rby = fminf(y2, bx[j][3]);
          float iw = fmaxf(rbx - ltx, 0.f);
          float ih = fmaxf(rby - lty, 0.f);
          float inter = iw * ih;
          float iou = inter / (ai + ar2[j] - inter + 1e-9f);
          if (iou > DET_T) cur |= 1ULL << b;
        }
      }
      sm[i][w] = cur;
    }
  }
  __syncthreads();
  __shared__ u64 kws[5];
  if (tid < 64) {
    u64 keep = 0;
    if (tid < 4) keep = ~0ULL;
    else if (tid == 4) keep = (1ULL << 44) - 1;  // 300 = 4*64 + 44
    for (int i = 0; i < POST; ++i) {
      u64 kw = __shfl(keep, i >> 6);
      if ((kw >> (i & 63)) & 1ULL) {
        if (tid < 5) keep &= ~sm[i][tid];
      }
    }
    if (tid < 5) kws[tid] = keep;
  }
  __syncthreads();
  __shared__ int sel[NDET];
  if (tid == 0) {
    int cnt = 0;
    for (int i = 0; i < POST && cnt < NDET; ++i) {
      bool kept = (kws[i >> 6] >> (i & 63)) & 1ULL;
      if (kept && fin[i]) sel[cnt++] = i;   // Class A: kept with finite score
    }
    for (int i = 0; i < POST && cnt < NDET; ++i) {
      bool kept = (kws[i >> 6] >> (i & 63)) & 1ULL;
      if (!(kept && fin[i])) sel[cnt++] = i;  // Class B: all -inf entries in top_k
    }
  }
  __syncthreads();
  if (tid < NDET) ridx[img * NDET + tid] = img * POST + ord[sel[tid]];
}

// ---------------- final gather into d_out: [pooled 200x1024][boxes 200x4][probs 200x1600] -------
__global__ __launch_bounds__(256) void gather_out(const int* __restrict__ ridx,
    const float* __restrict__ pooled, const float* __restrict__ pb,
    const float* __restrict__ clsp, float* __restrict__ out) {
  const int n = blockIdx.x;
  const int tid = threadIdx.x;
  const int row = ridx[n];
  for (int c = tid; c < CC; c += 256)
    out[(size_t)n * CC + c] = pooled[(size_t)row * CC + c];
  if (tid < 4)
    out[204800 + n * 4 + tid] = pb[row * 4 + tid];
  for (int c = tid; c < NCLS; c += 256)
    out[205600 + (size_t)n * NCLS + c] = clsp[(size_t)row * NCLS + c];
}

extern "C" void kernel_launch(void* const* d_in, const int* in_sizes, int n_in,
                              void* d_out, int out_size, void* d_ws, size_t ws_size,
                              hipStream_t stream) {
  (void)in_sizes; (void)n_in; (void)out_size;
  const int* isz = (const int*)d_in[1];
  const float* feat = (const float*)d_in[2];
  const float* convw = (const float*)d_in[3];
  const float* convb = (const float*)d_in[4];
  const float* objw = (const float*)d_in[5];
  const float* objb = (const float*)d_in[6];
  const float* dltw = (const float*)d_in[7];
  const float* dltb = (const float*)d_in[8];
  const float* clsw = (const float*)d_in[9];
  const float* clsb = (const float*)d_in[10];
  const float* boxw = (const float*)d_in[11];
  const float* boxb = (const float*)d_in[12];
  float* out = (float*)d_out;

  char* wsb = (char*)d_ws;
  size_t off = 0;
  auto alloc = [&](size_t bytes) -> void* {
    void* p = wsb + off;
    off = (off + bytes + 255) & ~(size_t)255;
    return p;
  };
  constexpr size_t TSZ = (size_t)CB * CHW * CC * 4;         // 31.1 MB
  float* t = (float*)alloc(TSZ);                            // partial ks=0 / t / later featT
  float* scores = (float*)alloc((size_t)CB * NANCH * 4);
  float* deltas = (float*)alloc((size_t)CB * NANCH * 4 * 4);
  float* selB = (float*)alloc((size_t)CB * PRE * 4 * 4);
  u64* mask = (u64*)alloc((size_t)CB * PRE * 32 * 8);
  float* pb = (float*)alloc((size_t)CB * POST * 4 * 4);
  float* pooled = (float*)alloc((size_t)CB * POST * CC * 4);
  float* logits = (float*)alloc((size_t)CB * POST * GN * 4);
  float* clsp = (float*)alloc((size_t)CB * POST * NCLS * 4);
  float* detbox = (float*)alloc((size_t)CB * POST * 4 * 4);
  float* dets = (float*)alloc((size_t)CB * POST * 4);
  int* ridx = (int*)alloc((size_t)CB * NDET * 4);
  if (off > ws_size) return;  // base layout must fit

  // K-split partial buffers allocated LAST: prefer 4-way, fallback 2-way, then none.
  size_t base_off = off;
  int nks = 1;
  float *p1 = t, *p2 = t, *p3 = t;
  if (base_off + 3 * (TSZ + 256) <= ws_size) {
    nks = 4;
    p1 = (float*)alloc(TSZ); p2 = (float*)alloc(TSZ); p3 = (float*)alloc(TSZ);
  } else if (base_off + (TSZ + 256) <= ws_size) {
    nks = 2;
    p1 = (float*)alloc(TSZ);
  }
  const int klen = CC / nks;

  conv3x3p<<<dim3(16 * nks, CH, CB), 256, 0, stream>>>(feat, convw, t, p1, p2, p3, klen);
  reduce_br<<<dim3((CB * CHW * CC) / 1024), 256, 0, stream>>>(p1, p2, p3, convb, t, nks);
  heads<<<dim3(CB * CHW / 16), 256, 0, stream>>>(t, objw, objb, dltw, dltb, scores, deltas);
  transp<<<dim3((CHW + 31) / 32, CC / 32, CB), dim3(32, 8), 0, stream>>>(feat, t);  // t := featT
  topk_props<<<dim3(CB), 1024, 0, stream>>>(scores, deltas, isz, selB);
  nms_mask<<<dim3(8, 4, CB), 256, 0, stream>>>(selB, mask);
  rpn_scan<<<dim3(CB), 64, 0, stream>>>(mask, selB, pb);
  roi_kernel<<<dim3(CB * POST), 256, 0, stream>>>(t, pb, pooled);
  fc_gemm<<<dim3(10, 26), 256, 0, stream>>>(pooled, clsw, clsb, boxw, boxb, logits);
  softmax_det<<<dim3(CB * POST), 256, 0, stream>>>(logits, pb, isz, clsp, detbox, dets);
  det_nms<<<dim3(CB), 512, 0, stream>>>(dets, detbox, ridx);
  gather_out<<<dim3(CB * NDET), 256, 0, stream>>>(ridx, pooled, pb, clsp, out);
}

// Round 6
// 4063.581 us; speedup vs baseline: 1.7755x; 1.3725x over previous
//
#include <hip/hip_runtime.h>
#include <cmath>

typedef unsigned long long u64;
typedef unsigned int u32;

constexpr int CB = 2;
constexpr int CC = 1024;
constexpr int CH = 50;
constexpr int CW = 76;
constexpr int CHW = CH * CW;        // 3800
constexpr int CA = 15;
constexpr int NANCH = CHW * CA;     // 57000
constexpr int PRE = 2000;
constexpr int POST = 300;
constexpr int NDET = 100;
constexpr int NCLS = 1600;
constexpr int GN = 1605;            // 1601 cls logits + 4 box deltas
constexpr float RPN_T = 0.7f;
constexpr float DET_T = 0.5f;
constexpr float SCORE_T_ = 0.05f;
constexpr float CLIPLOG = 4.135166556742356f;

__device__ __forceinline__ u32 fkey(float f) {
  u32 u = __float_as_uint(f);
  return (u & 0x80000000u) ? ~u : (u | 0x80000000u);
}

// ---------------- RPN 3x3 conv partials (no bias/relu), pixel-major ----------------
// v6 = v5 minus the VGPR cap (launch_bounds(256,5) forced 48 VGPR -> scratch spills ->
// 12.6 GB HBM traffic, round-5 PMC) and minus the same-address dummy LDS store (9.8M
// bank-conflict cycles). Structure unchanged: fully-unrolled 8-ic steps (imm-offset LDS),
// b128 broadcast input reads, stride-73 weights, 4-way K-split.
// Grid (16 octiles * nks, 50 y, 2 b), 256 thr = 4 waves x 19 px, 64 oc/block.
__global__ __launch_bounds__(256) void conv3x3p(
    const float* __restrict__ feat, const float* __restrict__ wgt,
    float* __restrict__ p0, float* __restrict__ p1,
    float* __restrict__ p2, float* __restrict__ p3, int klen) {
  __shared__ float wl[64][73];      // [oc][ic*9+tap]; odd stride 73 -> 2-way (free) reads
  __shared__ float inl[8][3][128];  // [ic][ky][wave*32 + f], f<24 staged; 16B-aligned slices
  const int bx = blockIdx.x;
  const int octile = bx & 15, ks = bx >> 4;
  const int y = blockIdx.y, b = blockIdx.z;
  const int oc0 = octile * 64;
  const int tid = threadIdx.x;
  const int lane = tid & 63;
  const int wid = tid >> 6;          // wave id = pixel group (4 x 19 px)
  const int x0 = wid * 19;
  float acc[19];
#pragma unroll
  for (int p = 0; p < 19; ++p) acc[p] = 0.f;
  const float* fb = feat + (size_t)b * CC * CHW;
  const int icbeg = ks * klen;
  for (int ic0 = icbeg; ic0 < icbeg + klen; ic0 += 8) {
    __syncthreads();
    // stage weights: 64 oc x 72 taps (8 ic x 9), coalesced global reads
    for (int l = tid; l < 64 * 72; l += 256) {
      int o = l / 72, k = l - o * 72;
      wl[o][k] = wgt[(size_t)(oc0 + o) * 9216 + ic0 * 9 + k];
    }
    // stage inputs: per-wave slices, slot f of wave w = global x (19w - 1 + f), f<24
    for (int l = tid; l < 8 * 3 * 128; l += 256) {
      int k = l & 127;
      int f = k & 31, w = k >> 5;
      if (f < 24) {
        int icr = l >> 7;            // ic*3 + r, 0..23
        int ic = icr / 3;
        int r = icr - ic * 3;
        int yy = y + r - 1;
        int x = 19 * w - 1 + f;
        float v = 0.f;
        if (yy >= 0 && yy < CH && (unsigned)x < (unsigned)CW)
          v = fb[(size_t)(ic0 + ic) * CHW + yy * CW + x];
        inl[ic][r][k] = v;
      }
    }
    __syncthreads();
#pragma unroll
    for (int ic = 0; ic < 8; ++ic) {
#pragma unroll
      for (int ky = 0; ky < 3; ++ky) {
        float inv[24];
        const float* ib = &inl[ic][ky][wid * 32];
#pragma unroll
        for (int q = 0; q < 6; ++q) {
          float4 v4 = *reinterpret_cast<const float4*>(ib + q * 4);  // b128 broadcast, imm offset
          inv[q * 4 + 0] = v4.x; inv[q * 4 + 1] = v4.y;
          inv[q * 4 + 2] = v4.z; inv[q * 4 + 3] = v4.w;
        }
        const int c = ic * 9 + ky * 3;
        const float w0 = wl[lane][c], w1 = wl[lane][c + 1], w2 = wl[lane][c + 2];
#pragma unroll
        for (int p = 0; p < 19; ++p) {
          acc[p] = fmaf(w0, inv[p], acc[p]);
          acc[p] = fmaf(w1, inv[p + 1], acc[p]);
          acc[p] = fmaf(w2, inv[p + 2], acc[p]);
        }
      }
    }
  }
  float* pp = (ks == 0) ? p0 : (ks == 1) ? p1 : (ks == 2) ? p2 : p3;
#pragma unroll
  for (int p = 0; p < 19; ++p) {
    int x = x0 + p;
    pp[((size_t)b * CHW + y * CW + x) * CC + oc0 + lane] = acc[p];
  }
}

// ---------------- t = relu(p0 + p1 + p2 + p3 + bias), in-place on t(=p0) ----------------
__global__ __launch_bounds__(256) void reduce_br(
    const float* __restrict__ p1, const float* __restrict__ p2,
    const float* __restrict__ p3, const float* __restrict__ bias,
    float* __restrict__ t, int nparts) {
  size_t i = ((size_t)blockIdx.x * 256 + threadIdx.x) * 4;
  float4 a = *reinterpret_cast<const float4*>(t + i);
  int oc = (int)(i & (CC - 1));
  const float4 bv = *reinterpret_cast<const float4*>(bias + oc);
  if (nparts > 1) {
    const float4 c = *reinterpret_cast<const float4*>(p1 + i);
    a.x += c.x; a.y += c.y; a.z += c.z; a.w += c.w;
  }
  if (nparts > 2) {
    const float4 c = *reinterpret_cast<const float4*>(p2 + i);
    a.x += c.x; a.y += c.y; a.z += c.z; a.w += c.w;
  }
  if (nparts > 3) {
    const float4 c = *reinterpret_cast<const float4*>(p3 + i);
    a.x += c.x; a.y += c.y; a.z += c.z; a.w += c.w;
  }
  a.x = fmaxf(a.x + bv.x, 0.f); a.y = fmaxf(a.y + bv.y, 0.f);
  a.z = fmaxf(a.z + bv.z, 0.f); a.w = fmaxf(a.w + bv.w, 0.f);
  *reinterpret_cast<float4*>(t + i) = a;
}

// ---------------- obj (15) & delta (60) 1x1 heads ----------------
// grid 475 (16 px each), 256 threads = 64 o-lanes x 4 pixel groups
__global__ __launch_bounds__(256) void heads(
    const float* __restrict__ t,
    const float* __restrict__ ow, const float* __restrict__ ob,
    const float* __restrict__ dw, const float* __restrict__ db,
    float* __restrict__ scores, float* __restrict__ deltas) {
  __shared__ float tl[16][64];
  __shared__ float wl[64][81];  // [k][o] o<75
  const int tid = threadIdx.x;
  const int px0 = blockIdx.x * 16;
  const int lo = tid & 63, pg = tid >> 6;
  float accA[4] = {0, 0, 0, 0}, accB[4] = {0, 0, 0, 0};
  for (int kc = 0; kc < CC; kc += 64) {
    __syncthreads();
    for (int l = tid; l < 16 * 64; l += 256) {
      int p = l >> 6, k = l & 63;
      tl[p][k] = t[(size_t)(px0 + p) * CC + kc + k];
    }
    for (int l = tid; l < 75 * 64; l += 256) {
      int o = l >> 6, k = l & 63;
      wl[k][o] = (o < 15) ? ow[o * CC + kc + k] : dw[(o - 15) * CC + kc + k];
    }
    __syncthreads();
#pragma unroll 8
    for (int k = 0; k < 64; ++k) {
      float w1 = wl[k][lo];
      float w2 = (lo < 11) ? wl[k][64 + lo] : 0.f;
#pragma unroll
      for (int p = 0; p < 4; ++p) {
        float tv = tl[pg * 4 + p][k];
        accA[p] = fmaf(w1, tv, accA[p]);
        accB[p] = fmaf(w2, tv, accB[p]);
      }
    }
  }
#pragma unroll
  for (int p = 0; p < 4; ++p) {
    int px = px0 + pg * 4 + p;
    int b = px / CHW, pix = px - b * CHW;
    {
      int o = lo;
      float v = accA[p];
      if (o < 15) {
        scores[(size_t)b * NANCH + (size_t)pix * CA + o] = v + ob[o];
      } else {
        int oo = o - 15;
        deltas[((size_t)b * NANCH + (size_t)pix * CA + (oo >> 2)) * 4 + (oo & 3)] = v + db[oo];
      }
    }
    if (lo < 11) {
      int oo = 64 + lo - 15;  // 49..59
      deltas[((size_t)b * NANCH + (size_t)pix * CA + (oo >> 2)) * 4 + (oo & 3)] = accB[p] + db[oo];
    }
  }
}

// ---------------- feat NCHW -> NHWC transpose (for coalesced roi_align) ----------------
__global__ __launch_bounds__(256) void transp(const float* __restrict__ in, float* __restrict__ outT) {
  __shared__ float tile[32][33];
  int b = blockIdx.z;
  int p0 = blockIdx.x * 32, c0 = blockIdx.y * 32;
  int tx = threadIdx.x, ty = threadIdx.y;
  for (int i = ty; i < 32; i += 8) {
    int p = p0 + tx;
    tile[i][tx] = (p < CHW) ? in[((size_t)b * CC + c0 + i) * CHW + p] : 0.f;
  }
  __syncthreads();
  for (int i = ty; i < 32; i += 8) {
    int p = p0 + i;
    if (p < CHW) outT[((size_t)b * CHW + p) * CC + c0 + tx] = tile[tx][i];
  }
}

// ---------------- exact top-2000 (radix threshold + bitonic sort) + proposal decode + clip ------
// grid 2 (per image), 1024 threads
__global__ __launch_bounds__(1024) void topk_props(
    const float* __restrict__ scores, const float* __restrict__ deltas,
    const int* __restrict__ isz, float* __restrict__ selB) {
  const int img = blockIdx.x;
  const int tid = threadIdx.x;
  const float* sc = scores + (size_t)img * NANCH;
  __shared__ u32 hist[256];
  __shared__ u32 s_prefix, s_need, s_cnt;
  __shared__ u64 arr[4096];

  u32 prefix = 0, need = PRE;
  for (int byte = 3; byte >= 0; --byte) {
    if (tid < 256) hist[tid] = 0;
    __syncthreads();
    for (int i = tid; i < NANCH; i += 1024) {
      u32 key = fkey(sc[i]);
      bool ok = (byte == 3) || ((key >> (8 * byte + 8)) == prefix);
      if (ok) atomicAdd(&hist[(key >> (8 * byte)) & 255], 1u);
    }
    __syncthreads();
    if (tid == 0) {
      u32 cum = 0;
      int bin;
      for (bin = 255; bin >= 0; --bin) {
        cum += hist[bin];
        if (cum >= need) break;
      }
      s_need = need - (cum - hist[bin]);
      s_prefix = (prefix << 8) | (u32)bin;
    }
    __syncthreads();
    prefix = s_prefix;
    need = s_need;
    __syncthreads();
  }
  const u32 T = prefix;  // count(key>T) < PRE <= count(key>=T)
  if (tid == 0) s_cnt = 0;
  __syncthreads();
  for (int i = tid; i < NANCH; i += 1024) {
    u32 key = fkey(sc[i]);
    if (key >= T) {
      u32 p = atomicAdd(&s_cnt, 1u);
      if (p < 4096) arr[p] = ((u64)(~key) << 32) | (u32)i;  // ascending rank = score desc, idx asc
    }
  }
  __syncthreads();
  int n = (int)(s_cnt < 4096u ? s_cnt : 4096u);
  for (int i = tid; i < 4096; i += 1024)
    if (i >= n) arr[i] = ~0ULL;
  __syncthreads();
  for (int kk = 2; kk <= 4096; kk <<= 1) {
    for (int j = kk >> 1; j > 0; j >>= 1) {
      for (int i = tid; i < 4096; i += 1024) {
        int ixj = i ^ j;
        if (ixj > i) {
          u64 a = arr[i], bb = arr[ixj];
          bool up = ((i & kk) == 0);
          if ((a > bb) == up) { arr[i] = bb; arr[ixj] = a; }
        }
      }
      __syncthreads();
    }
  }
  // decode anchor + apply deltas + clip for the top PRE (sorted)
  const float h_img = (float)isz[img * 2 + 0];
  const float w_img = (float)isz[img * 2 + 1];
  const float* dl = deltas + (size_t)img * NANCH * 4;
  for (int k = tid; k < PRE; k += 1024) {
    u32 idx = (u32)arr[k];
    int aa = (int)(idx % 15u);
    int p = (int)(idx / 15u);
    int xx = p % CW, yy = p / CW;
    double szd = 32.0 * (double)(1 << (aa / 3));
    double rr = 0.5 * (double)(1 << (aa % 3));
    double wd = szd * sqrt(1.0 / rr);
    double hd = wd * rr;
    float ax1 = (float)(xx * 16) + (float)(-wd * 0.5);
    float ax2 = (float)(xx * 16) + (float)(wd * 0.5);
    float ay1 = (float)(yy * 16) + (float)(-hd * 0.5);
    float ay2 = (float)(yy * 16) + (float)(hd * 0.5);
    float aw = ax2 - ax1, ah = ay2 - ay1;
    float cx = ax1 + 0.5f * aw, cy = ay1 + 0.5f * ah;
    float d0 = dl[(size_t)idx * 4 + 0], d1 = dl[(size_t)idx * 4 + 1];
    float d2 = dl[(size_t)idx * 4 + 2], d3 = dl[(size_t)idx * 4 + 3];
    float dwv = fminf(d2, CLIPLOG), dhv = fminf(d3, CLIPLOG);
    float pcx = d0 * aw + cx, pcy = d1 * ah + cy;
    float pw = expf(dwv) * aw, ph = expf(dhv) * ah;
    float x1 = pcx - 0.5f * pw, y1 = pcy - 0.5f * ph;
    float x2 = pcx + 0.5f * pw, y2 = pcy + 0.5f * ph;
    x1 = fminf(fmaxf(x1, 0.f), w_img);
    y1 = fminf(fmaxf(y1, 0.f), h_img);
    x2 = fminf(fmaxf(x2, 0.f), w_img);
    y2 = fminf(fmaxf(y2, 0.f), h_img);
    float* o = selB + ((size_t)img * PRE + k) * 4;
    o[0] = x1; o[1] = y1; o[2] = x2; o[3] = y2;
  }
}

// ---------------- RPN NMS suppression-mask build ----------------
// grid (8 rowblocks, 4 j-splits, 2 img), 256 threads
__global__ __launch_bounds__(256) void nms_mask(const float* __restrict__ selB, u64* __restrict__ mask) {
  const int img = blockIdx.z;
  const int jr0 = blockIdx.y * 512;
  const int i = blockIdx.x * 256 + threadIdx.x;  // 0..2047
  __shared__ float bx[PRE][4];
  __shared__ float ar[PRE];
  const int tid = threadIdx.x;
  for (int l = tid; l < PRE * 4; l += 256) bx[l >> 2][l & 3] = selB[(size_t)img * PRE * 4 + l];
  __syncthreads();
  for (int l = tid; l < PRE; l += 256) ar[l] = (bx[l][2] - bx[l][0]) * (bx[l][3] - bx[l][1]);
  __syncthreads();
  float x1 = 0, y1 = 0, x2 = 0, y2 = 0, ai = 0;
  if (i < PRE) { x1 = bx[i][0]; y1 = bx[i][1]; x2 = bx[i][2]; y2 = bx[i][3]; ai = ar[i]; }
  u64 cur = 0;
  for (int j = jr0; j < jr0 + 512; ++j) {
    bool bit = false;
    if (i < PRE && j < PRE && j > i) {
      float ltx = fmaxf(x1, bx[j][0]);
      float lty = fmaxf(y1, bx[j][1]);
      float rbx = fminf(x2, bx[j][2]);
      float rby = fminf(y2, bx[j][3]);
      float iw = fmaxf(rbx - ltx, 0.f);
      float ih = fmaxf(rby - lty, 0.f);
      float inter = iw * ih;
      float iou = inter / (ai + ar[j] - inter + 1e-9f);
      bit = iou > RPN_T;
    }
    cur |= ((u64)bit) << (j & 63);
    if ((j & 63) == 63) {
      if (i < PRE) mask[((size_t)img * PRE + i) * 32 + (j >> 6)] = cur;
      cur = 0;
    }
  }
}

// ---------------- RPN NMS serial scan + keep-list + box gather ----------------
// grid 2, 64 threads (one wave)
__global__ __launch_bounds__(64) void rpn_scan(const u64* __restrict__ mask,
    const float* __restrict__ selB, float* __restrict__ pb) {
  const int img = blockIdx.x;
  const int lane = threadIdx.x;
  const u64* mrow = mask + (size_t)img * PRE * 32;
  u64 keep = 0;
  if (lane < 31) keep = ~0ULL;
  else if (lane == 31) keep = (1ULL << 16) - 1;  // 2000 = 31*64 + 16
  for (int c = 0; c < PRE; c += 8) {
    u64 m0 = 0, m1 = 0, m2 = 0, m3 = 0, m4 = 0, m5 = 0, m6 = 0, m7 = 0;
    if (lane < 32) {
      const u64* p = mrow + (size_t)c * 32 + lane;
      m0 = p[0];   m1 = p[32];  m2 = p[64];  m3 = p[96];
      m4 = p[128]; m5 = p[160]; m6 = p[192]; m7 = p[224];
    }
#pragma unroll
    for (int k = 0; k < 8; ++k) {
      int i = c + k;
      u64 kw = __shfl(keep, i >> 6);
      if ((kw >> (i & 63)) & 1ULL) {
        u64 mm = (k == 0) ? m0 : (k == 1) ? m1 : (k == 2) ? m2 : (k == 3) ? m3
               : (k == 4) ? m4 : (k == 5) ? m5 : (k == 6) ? m6 : m7;
        keep &= ~mm;
      }
    }
  }
  __shared__ u64 kws[32];
  __shared__ int rows[POST];
  if (lane < 32) kws[lane] = keep;
  __syncthreads();
  if (lane == 0) {
    int cnt = 0;
    for (int w = 0; w < 32 && cnt < POST; ++w) {
      u64 kv = kws[w];
      while (kv && cnt < POST) {
        int b = __ffsll((unsigned long long)kv) - 1;
        int i = w * 64 + b;
        if (i < PRE) rows[cnt++] = i;
        kv &= kv - 1;
      }
    }
    for (int w = 0; w < 32 && cnt < POST; ++w) {
      u64 kv = ~kws[w];
      while (kv && cnt < POST) {
        int b = __ffsll((unsigned long long)kv) - 1;
        int i = w * 64 + b;
        if (i < PRE) rows[cnt++] = i;
        kv &= kv - 1;
      }
    }
  }
  __syncthreads();
  for (int k = lane; k < POST; k += 64) {
    int row = rows[k];
    const float* s = selB + ((size_t)img * PRE + row) * 4;
    float* d = pb + ((size_t)img * POST + k) * 4;
    d[0] = s[0]; d[1] = s[1]; d[2] = s[2]; d[3] = s[3];
  }
}

// ---------------- RoI align (7x7, mean) on NHWC feat ----------------
// grid 600 (one box), 256 threads (4 channels each)
__global__ __launch_bounds__(256) void roi_kernel(const float* __restrict__ featT,
    const float* __restrict__ pb, float* __restrict__ pooled) {
  const int box = blockIdx.x;
  const int img = box / POST;
  const int tid = threadIdx.x;
  const float scl = 0.0625f;
  float x1 = pb[box * 4 + 0] * scl, y1 = pb[box * 4 + 1] * scl;
  float x2 = pb[box * 4 + 2] * scl, y2 = pb[box * 4 + 3] * scl;
  const float* fb = featT + (size_t)img * CHW * CC;
  const int c0 = tid * 4;
  float a0 = 0, a1 = 0, a2 = 0, a3 = 0;
  for (int by = 0; by < 7; ++by) {
    float gy = ((float)by + 0.5f) / 7.0f;
    float ys = y1 + gy * (y2 - y1) - 0.5f;
    float yf = floorf(ys);
    float ly = ys - yf;
    int y0i = (int)yf;
    y0i = y0i < 0 ? 0 : (y0i > CH - 1 ? CH - 1 : y0i);
    int y1i = (y0i + 1 > CH - 1) ? CH - 1 : y0i + 1;
    for (int bx2 = 0; bx2 < 7; ++bx2) {
      float gx = ((float)bx2 + 0.5f) / 7.0f;
      float xs = x1 + gx * (x2 - x1) - 0.5f;
      float xf = floorf(xs);
      float lx = xs - xf;
      int x0i = (int)xf;
      x0i = x0i < 0 ? 0 : (x0i > CW - 1 ? CW - 1 : x0i);
      int x1i = (x0i + 1 > CW - 1) ? CW - 1 : x0i + 1;
      float w00 = (1.f - ly) * (1.f - lx), w01 = (1.f - ly) * lx;
      float w10 = ly * (1.f - lx), w11 = ly * lx;
      const float4 v00 = *reinterpret_cast<const float4*>(fb + ((size_t)y0i * CW + x0i) * CC + c0);
      const float4 v01 = *reinterpret_cast<const float4*>(fb + ((size_t)y0i * CW + x1i) * CC + c0);
      const float4 v10 = *reinterpret_cast<const float4*>(fb + ((size_t)y1i * CW + x0i) * CC + c0);
      const float4 v11 = *reinterpret_cast<const float4*>(fb + ((size_t)y1i * CW + x1i) * CC + c0);
      a0 += w00 * v00.x + w01 * v01.x + w10 * v10.x + w11 * v11.x;
      a1 += w00 * v00.y + w01 * v01.y + w10 * v10.y + w11 * v11.y;
      a2 += w00 * v00.z + w01 * v01.z + w10 * v10.z + w11 * v11.z;
      a3 += w00 * v00.w + w01 * v01.w + w10 * v10.w + w11 * v11.w;
    }
  }
  float* o = pooled + (size_t)box * CC + c0;
  o[0] = a0 / 49.f; o[1] = a1 / 49.f; o[2] = a2 / 49.f; o[3] = a3 / 49.f;
}

// ---------------- FC: logits[600][1605] = pooled @ [cls_w;box_w]^T + bias ----------------
__global__ __launch_bounds__(256) void fc_gemm(const float* __restrict__ pooled,
    const float* __restrict__ clsw, const float* __restrict__ clsb,
    const float* __restrict__ boxw, const float* __restrict__ boxb,
    float* __restrict__ logits) {
  __shared__ float As[32][65];
  __shared__ float Bs[32][65];
  const int m0 = blockIdx.x * 64;
  const int n0 = blockIdx.y * 64;
  const int tid = threadIdx.x;
  const int tm = tid & 15, tn = tid >> 4;
  float acc[4][4] = {};
  for (int kc = 0; kc < CC; kc += 32) {
    __syncthreads();
    for (int l = tid; l < 2048; l += 256) {
      int mm = l >> 5, kk = l & 31;
      int mA = m0 + mm;
      As[kk][mm] = (mA < CB * POST) ? pooled[(size_t)mA * CC + kc + kk] : 0.f;
      int nB = n0 + mm;
      float bv = 0.f;
      if (nB < 1601) bv = clsw[(size_t)nB * CC + kc + kk];
      else if (nB < GN) bv = boxw[(size_t)(nB - 1601) * CC + kc + kk];
      Bs[kk][mm] = bv;
    }
    __syncthreads();
#pragma unroll
    for (int kk = 0; kk < 32; ++kk) {
      float a[4], b[4];
#pragma unroll
      for (int ii = 0; ii < 4; ++ii) a[ii] = As[kk][tm * 4 + ii];
#pragma unroll
      for (int jj = 0; jj < 4; ++jj) b[jj] = Bs[kk][tn * 4 + jj];
#pragma unroll
      for (int ii = 0; ii < 4; ++ii)
#pragma unroll
        for (int jj = 0; jj < 4; ++jj)
          acc[ii][jj] = fmaf(a[ii], b[jj], acc[ii][jj]);
    }
  }
  for (int ii = 0; ii < 4; ++ii) {
    int mA = m0 + tm * 4 + ii;
    if (mA >= CB * POST) continue;
    for (int jj = 0; jj < 4; ++jj) {
      int nB = n0 + tn * 4 + jj;
      if (nB >= GN) continue;
      float bias = (nB < 1601) ? clsb[nB] : boxb[nB - 1601];
      logits[(size_t)mA * GN + nB] = acc[ii][jj] + bias;
    }
  }
}

// ---------------- softmax (1601) -> cls_probs (1600), msc, det box decode + clip, score gate ----
__global__ __launch_bounds__(256) void softmax_det(
    const float* __restrict__ logits, const float* __restrict__ pb,
    const int* __restrict__ isz, float* __restrict__ clsp,
    float* __restrict__ detbox, float* __restrict__ dets) {
  const int row = blockIdx.x;
  const int tid = threadIdx.x;
  const float* lr = logits + (size_t)row * GN;
  __shared__ float red[256];
  float m = -INFINITY;
  for (int c = tid; c < 1600; c += 256) m = fmaxf(m, lr[c]);
  red[tid] = m;
  __syncthreads();
  for (int s = 128; s > 0; s >>= 1) {
    if (tid < s) red[tid] = fmaxf(red[tid], red[tid + s]);
    __syncthreads();
  }
  const float m1600 = red[0];
  __syncthreads();
  const float mall = fmaxf(m1600, lr[1600]);
  float sum = 0.f;
  for (int c = tid; c < 1601; c += 256) sum += expf(lr[c] - mall);
  red[tid] = sum;
  __syncthreads();
  for (int s = 128; s > 0; s >>= 1) {
    if (tid < s) red[tid] += red[tid + s];
    __syncthreads();
  }
  const float ssum = red[0];
  for (int c = tid; c < 1600; c += 256)
    clsp[(size_t)row * NCLS + c] = expf(lr[c] - mall) / ssum;
  if (tid == 0) {
    float msc = expf(m1600 - mall) / ssum;
    int img = row / POST;
    float hh = (float)isz[img * 2 + 0], ww = (float)isz[img * 2 + 1];
    float bx1 = pb[row * 4 + 0], by1 = pb[row * 4 + 1];
    float bx2 = pb[row * 4 + 2], by2 = pb[row * 4 + 3];
    float w = bx2 - bx1, h = by2 - by1;
    float cx = bx1 + 0.5f * w, cy = by1 + 0.5f * h;
    float d0 = lr[1601] / 10.0f, d1 = lr[1602] / 10.0f;
    float d2 = fminf(lr[1603] / 5.0f, CLIPLOG), d3 = fminf(lr[1604] / 5.0f, CLIPLOG);
    float pcx = d0 * w + cx, pcy = d1 * h + cy;
    float pw = expf(d2) * w, ph = expf(d3) * h;
    float xx1 = pcx - 0.5f * pw, yy1 = pcy - 0.5f * ph;
    float xx2 = pcx + 0.5f * pw, yy2 = pcy + 0.5f * ph;
    xx1 = fminf(fmaxf(xx1, 0.f), ww);
    xx2 = fminf(fmaxf(xx2, 0.f), ww);
    yy1 = fminf(fmaxf(yy1, 0.f), hh);
    yy2 = fminf(fmaxf(yy2, 0.f), hh);
    detbox[row * 4 + 0] = xx1; detbox[row * 4 + 1] = yy1;
    detbox[row * 4 + 2] = xx2; detbox[row * 4 + 3] = yy2;
    dets[row] = msc > SCORE_T_ ? msc : -INFINITY;
  }
}

// ---------------- det NMS (sort 300 + mask + scan + top_k-exact selection) -> global rows -------
// Selection replicates top_k(where(keep, s, -inf), 100):
//   Class A: kept AND finite score, ascending sorted position (s sorted desc);
//   Class B: everything else (suppressed OR kept-with--inf), ascending position.
__global__ __launch_bounds__(512) void det_nms(const float* __restrict__ dets,
    const float* __restrict__ detbox, int* __restrict__ ridx) {
  const int img = blockIdx.x;
  const int tid = threadIdx.x;
  __shared__ u64 arr[512];
  {
    u64 v = ~0ULL;
    if (tid < POST) {
      u32 key = fkey(dets[img * POST + tid]);
      v = ((u64)(~key) << 32) | (u32)tid;  // ascending = score desc, idx asc (stable argsort(-s))
    }
    arr[tid] = v;
  }
  __syncthreads();
  for (int kk = 2; kk <= 512; kk <<= 1) {
    for (int j = kk >> 1; j > 0; j >>= 1) {
      int ixj = tid ^ j;
      if (ixj > tid) {
        u64 a = arr[tid], bb = arr[ixj];
        bool up = ((tid & kk) == 0);
        if ((a > bb) == up) { arr[tid] = bb; arr[ixj] = a; }
      }
      __syncthreads();
    }
  }
  __shared__ float bx[POST][4];
  __shared__ float ar2[POST];
  __shared__ int ord[POST];
  __shared__ unsigned char fin[POST];
  if (tid < POST) {
    int o = (int)(u32)arr[tid];
    ord[tid] = o;
    fin[tid] = (dets[img * POST + o] != -INFINITY) ? 1 : 0;
    const float* s = detbox + ((size_t)img * POST + o) * 4;
    bx[tid][0] = s[0]; bx[tid][1] = s[1]; bx[tid][2] = s[2]; bx[tid][3] = s[3];
    ar2[tid] = (s[2] - s[0]) * (s[3] - s[1]);
  }
  __syncthreads();
  __shared__ u64 sm[POST][5];
  if (tid < POST) {
    const int i = tid;
    float x1 = bx[i][0], y1 = bx[i][1], x2 = bx[i][2], y2 = bx[i][3], ai = ar2[i];
    for (int w = 0; w < 5; ++w) {
      u64 cur = 0;
      for (int b = 0; b < 64; ++b) {
        int j = w * 64 + b;
        if (j < POST && j > i) {
          float ltx = fmaxf(x1, bx[j][0]);
          float lty = fmaxf(y1, bx[j][1]);
          float rbx = fminf(x2, bx[j][2]);
          float rby = fminf(y2, bx[j][3]);
          float iw = fmaxf(rbx - ltx, 0.f);
          float ih = fmaxf(rby - lty, 0.f);
          float inter = iw * ih;
          float iou = inter / (ai + ar2[j] - inter + 1e-9f);
          if (iou > DET_T) cur |= 1ULL << b;
        }
      }
      sm[i][w] = cur;
    }
  }
  __syncthreads();
  __shared__ u64 kws[5];
  if (tid < 64) {
    u64 keep = 0;
    if (tid < 4) keep = ~0ULL;
    else if (tid == 4) keep = (1ULL << 44) - 1;  // 300 = 4*64 + 44
    for (int i = 0; i < POST; ++i) {
      u64 kw = __shfl(keep, i >> 6);
      if ((kw >> (i & 63)) & 1ULL) {
        if (tid < 5) keep &= ~sm[i][tid];
      }
    }
    if (tid < 5) kws[tid] = keep;
  }
  __syncthreads();
  __shared__ int sel[NDET];
  if (tid == 0) {
    int cnt = 0;
    for (int i = 0; i < POST && cnt < NDET; ++i) {
      bool kept = (kws[i >> 6] >> (i & 63)) & 1ULL;
      if (kept && fin[i]) sel[cnt++] = i;   // Class A: kept with finite score
    }
    for (int i = 0; i < POST && cnt < NDET; ++i) {
      bool kept = (kws[i >> 6] >> (i & 63)) & 1ULL;
      if (!(kept && fin[i])) sel[cnt++] = i;  // Class B: all -inf entries in top_k
    }
  }
  __syncthreads();
  if (tid < NDET) ridx[img * NDET + tid] = img * POST + ord[sel[tid]];
}

// ---------------- final gather into d_out: [pooled 200x1024][boxes 200x4][probs 200x1600] -------
__global__ __launch_bounds__(256) void gather_out(const int* __restrict__ ridx,
    const float* __restrict__ pooled, const float* __restrict__ pb,
    const float* __restrict__ clsp, float* __restrict__ out) {
  const int n = blockIdx.x;
  const int tid = threadIdx.x;
  const int row = ridx[n];
  for (int c = tid; c < CC; c += 256)
    out[(size_t)n * CC + c] = pooled[(size_t)row * CC + c];
  if (tid < 4)
    out[204800 + n * 4 + tid] = pb[row * 4 + tid];
  for (int c = tid; c < NCLS; c += 256)
    out[205600 + (size_t)n * NCLS + c] = clsp[(size_t)row * NCLS + c];
}

extern "C" void kernel_launch(void* const* d_in, const int* in_sizes, int n_in,
                              void* d_out, int out_size, void* d_ws, size_t ws_size,
                              hipStream_t stream) {
  (void)in_sizes; (void)n_in; (void)out_size;
  const int* isz = (const int*)d_in[1];
  const float* feat = (const float*)d_in[2];
  const float* convw = (const float*)d_in[3];
  const float* convb = (const float*)d_in[4];
  const float* objw = (const float*)d_in[5];
  const float* objb = (const float*)d_in[6];
  const float* dltw = (const float*)d_in[7];
  const float* dltb = (const float*)d_in[8];
  const float* clsw = (const float*)d_in[9];
  const float* clsb = (const float*)d_in[10];
  const float* boxw = (const float*)d_in[11];
  const float* boxb = (const float*)d_in[12];
  float* out = (float*)d_out;

  char* wsb = (char*)d_ws;
  size_t off = 0;
  auto alloc = [&](size_t bytes) -> void* {
    void* p = wsb + off;
    off = (off + bytes + 255) & ~(size_t)255;
    return p;
  };
  constexpr size_t TSZ = (size_t)CB * CHW * CC * 4;         // 31.1 MB
  float* t = (float*)alloc(TSZ);                            // partial ks=0 / t / later featT
  float* scores = (float*)alloc((size_t)CB * NANCH * 4);
  float* deltas = (float*)alloc((size_t)CB * NANCH * 4 * 4);
  float* selB = (float*)alloc((size_t)CB * PRE * 4 * 4);
  u64* mask = (u64*)alloc((size_t)CB * PRE * 32 * 8);
  float* pb = (float*)alloc((size_t)CB * POST * 4 * 4);
  float* pooled = (float*)alloc((size_t)CB * POST * CC * 4);
  float* logits = (float*)alloc((size_t)CB * POST * GN * 4);
  float* clsp = (float*)alloc((size_t)CB * POST * NCLS * 4);
  float* detbox = (float*)alloc((size_t)CB * POST * 4 * 4);
  float* dets = (float*)alloc((size_t)CB * POST * 4);
  int* ridx = (int*)alloc((size_t)CB * NDET * 4);
  if (off > ws_size) return;  // base layout must fit

  // K-split partial buffers allocated LAST: prefer 4-way, fallback 2-way, then none.
  size_t base_off = off;
  int nks = 1;
  float *p1 = t, *p2 = t, *p3 = t;
  if (base_off + 3 * (TSZ + 256) <= ws_size) {
    nks = 4;
    p1 = (float*)alloc(TSZ); p2 = (float*)alloc(TSZ); p3 = (float*)alloc(TSZ);
  } else if (base_off + (TSZ + 256) <= ws_size) {
    nks = 2;
    p1 = (float*)alloc(TSZ);
  }
  const int klen = CC / nks;

  conv3x3p<<<dim3(16 * nks, CH, CB), 256, 0, stream>>>(feat, convw, t, p1, p2, p3, klen);
  reduce_br<<<dim3((CB * CHW * CC) / 1024), 256, 0, stream>>>(p1, p2, p3, convb, t, nks);
  heads<<<dim3(CB * CHW / 16), 256, 0, stream>>>(t, objw, objb, dltw, dltb, scores, deltas);
  transp<<<dim3((CHW + 31) / 32, CC / 32, CB), dim3(32, 8), 0, stream>>>(feat, t);  // t := featT
  topk_props<<<dim3(CB), 1024, 0, stream>>>(scores, deltas, isz, selB);
  nms_mask<<<dim3(8, 4, CB), 256, 0, stream>>>(selB, mask);
  rpn_scan<<<dim3(CB), 64, 0, stream>>>(mask, selB, pb);
  roi_kernel<<<dim3(CB * POST), 256, 0, stream>>>(t, pb, pooled);
  fc_gemm<<<dim3(10, 26), 256, 0, stream>>>(pooled, clsw, clsb, boxw, boxb, logits);
  softmax_det<<<dim3(CB * POST), 256, 0, stream>>>(logits, pb, isz, clsp, detbox, dets);
  det_nms<<<dim3(CB), 512, 0, stream>>>(dets, detbox, ridx);
  gather_out<<<dim3(CB * NDET), 256, 0, stream>>>(ridx, pooled, pb, clsp, out);
}

// Round 7
// 3195.446 us; speedup vs baseline: 2.2578x; 1.2717x over previous
//
#include <hip/hip_runtime.h>
#include <cmath>

typedef unsigned long long u64;
typedef unsigned int u32;

constexpr int CB = 2;
constexpr int CC = 1024;
constexpr int CH = 50;
constexpr int CW = 76;
constexpr int CHW = CH * CW;        // 3800
constexpr int CA = 15;
constexpr int NANCH = CHW * CA;     // 57000
constexpr int PRE = 2000;
constexpr int POST = 300;
constexpr int NDET = 100;
constexpr int NCLS = 1600;
constexpr int GN = 1605;            // 1601 cls logits + 4 box deltas
constexpr float RPN_T = 0.7f;
constexpr float DET_T = 0.5f;
constexpr float SCORE_T_ = 0.05f;
constexpr float CLIPLOG = 4.135166556742356f;

__device__ __forceinline__ u32 fkey(float f) {
  u32 u = __float_as_uint(f);
  return (u & 0x80000000u) ? ~u : (u | 0x80000000u);
}

// ---------------- RPN 3x3 conv partials (no bias/relu), pixel-major ----------------
// v7 = v6 + 2 oc/thread (oc = oc0+lane and oc0+64+lane), 128 oc/block, 8 octiles.
// Rationale (round-6 PMC model): v6 was LDS-issue-bound — 144 b128 input broadcasts
// per wave-step fed only 2736 FMA-cyc. 2 oc doubles FMA per input read: per-output
// LDS cost drops ~40%. Everything that fixed earlier failures is kept: b128 inputs,
// fully-unrolled imm-offset LDS, div-free weight staging, no VGPR cap, 4-way K-split.
// Grid (8 octiles * nks, 50 y, 2 b), 256 thr = 4 waves x 19 px.
__global__ __launch_bounds__(256) void conv3x3p(
    const float* __restrict__ feat, const float* __restrict__ wgt,
    float* __restrict__ p0, float* __restrict__ p1,
    float* __restrict__ p2, float* __restrict__ p3, int klen) {
  __shared__ float wl[128][73];     // [oc][ic*9+tap]; odd stride 73 -> 2-way (free) reads
  __shared__ float inl[8][3][128];  // [ic][ky][wave*32 + f], f<24 staged; 16B-aligned slices
  const int bx = blockIdx.x;
  const int octile = bx & 7, ks = bx >> 3;
  const int y = blockIdx.y, b = blockIdx.z;
  const int oc0 = octile * 128;
  const int tid = threadIdx.x;
  const int lane = tid & 63;
  const int wid = tid >> 6;          // wave id = pixel group (4 x 19 px)
  const int x0 = wid * 19;
  float acc0[19], acc1[19];
#pragma unroll
  for (int p = 0; p < 19; ++p) { acc0[p] = 0.f; acc1[p] = 0.f; }
  const float* fb = feat + (size_t)b * CC * CHW;
  const int icbeg = ks * klen;
  const int wrow = tid >> 1;         // weight staging: thread pair covers one oc row
  const int whal = (tid & 1) * 36;
  for (int ic0 = icbeg; ic0 < icbeg + klen; ic0 += 8) {
    __syncthreads();
    // stage weights: 128 oc x 72 taps (8 ic x 9); div-free addressing
    {
      const float* wsrc = wgt + (size_t)(oc0 + wrow) * 9216 + ic0 * 9 + whal;
      float* wdst = &wl[wrow][whal];
#pragma unroll
      for (int j = 0; j < 36; ++j) wdst[j] = wsrc[j];
    }
    // stage inputs: per-wave slices, slot f of wave w = global x (19w - 1 + f), f<24
    for (int l = tid; l < 8 * 3 * 128; l += 256) {
      int k = l & 127;
      int f = k & 31, w = k >> 5;
      if (f < 24) {
        int icr = l >> 7;            // ic*3 + r, 0..23
        int ic = icr / 3;
        int r = icr - ic * 3;
        int yy = y + r - 1;
        int x = 19 * w - 1 + f;
        float v = 0.f;
        if (yy >= 0 && yy < CH && (unsigned)x < (unsigned)CW)
          v = fb[(size_t)(ic0 + ic) * CHW + yy * CW + x];
        inl[ic][r][k] = v;
      }
    }
    __syncthreads();
#pragma unroll
    for (int ic = 0; ic < 8; ++ic) {
#pragma unroll
      for (int ky = 0; ky < 3; ++ky) {
        float inv[24];
        const float* ib = &inl[ic][ky][wid * 32];
#pragma unroll
        for (int q = 0; q < 6; ++q) {
          float4 v4 = *reinterpret_cast<const float4*>(ib + q * 4);  // b128 broadcast, imm offset
          inv[q * 4 + 0] = v4.x; inv[q * 4 + 1] = v4.y;
          inv[q * 4 + 2] = v4.z; inv[q * 4 + 3] = v4.w;
        }
        const int c = ic * 9 + ky * 3;
        const float w0a = wl[lane][c], w1a = wl[lane][c + 1], w2a = wl[lane][c + 2];
        const float w0b = wl[64 + lane][c], w1b = wl[64 + lane][c + 1], w2b = wl[64 + lane][c + 2];
#pragma unroll
        for (int p = 0; p < 19; ++p) {
          acc0[p] = fmaf(w0a, inv[p], acc0[p]);
          acc0[p] = fmaf(w1a, inv[p + 1], acc0[p]);
          acc0[p] = fmaf(w2a, inv[p + 2], acc0[p]);
          acc1[p] = fmaf(w0b, inv[p], acc1[p]);
          acc1[p] = fmaf(w1b, inv[p + 1], acc1[p]);
          acc1[p] = fmaf(w2b, inv[p + 2], acc1[p]);
        }
      }
    }
  }
  float* pp = (ks == 0) ? p0 : (ks == 1) ? p1 : (ks == 2) ? p2 : p3;
#pragma unroll
  for (int p = 0; p < 19; ++p) {
    int x = x0 + p;
    float* tp = pp + ((size_t)b * CHW + y * CW + x) * CC + oc0;
    tp[lane] = acc0[p];
    tp[64 + lane] = acc1[p];
  }
}

// ---------------- t = relu(p0 + p1 + p2 + p3 + bias), in-place on t(=p0) ----------------
__global__ __launch_bounds__(256) void reduce_br(
    const float* __restrict__ p1, const float* __restrict__ p2,
    const float* __restrict__ p3, const float* __restrict__ bias,
    float* __restrict__ t, int nparts) {
  size_t i = ((size_t)blockIdx.x * 256 + threadIdx.x) * 4;
  float4 a = *reinterpret_cast<const float4*>(t + i);
  int oc = (int)(i & (CC - 1));
  const float4 bv = *reinterpret_cast<const float4*>(bias + oc);
  if (nparts > 1) {
    const float4 c = *reinterpret_cast<const float4*>(p1 + i);
    a.x += c.x; a.y += c.y; a.z += c.z; a.w += c.w;
  }
  if (nparts > 2) {
    const float4 c = *reinterpret_cast<const float4*>(p2 + i);
    a.x += c.x; a.y += c.y; a.z += c.z; a.w += c.w;
  }
  if (nparts > 3) {
    const float4 c = *reinterpret_cast<const float4*>(p3 + i);
    a.x += c.x; a.y += c.y; a.z += c.z; a.w += c.w;
  }
  a.x = fmaxf(a.x + bv.x, 0.f); a.y = fmaxf(a.y + bv.y, 0.f);
  a.z = fmaxf(a.z + bv.z, 0.f); a.w = fmaxf(a.w + bv.w, 0.f);
  *reinterpret_cast<float4*>(t + i) = a;
}

// ---------------- obj (15) & delta (60) 1x1 heads ----------------
// grid 475 (16 px each), 256 threads = 64 o-lanes x 4 pixel groups
__global__ __launch_bounds__(256) void heads(
    const float* __restrict__ t,
    const float* __restrict__ ow, const float* __restrict__ ob,
    const float* __restrict__ dw, const float* __restrict__ db,
    float* __restrict__ scores, float* __restrict__ deltas) {
  __shared__ float tl[16][64];
  __shared__ float wl[64][81];  // [k][o] o<75
  const int tid = threadIdx.x;
  const int px0 = blockIdx.x * 16;
  const int lo = tid & 63, pg = tid >> 6;
  float accA[4] = {0, 0, 0, 0}, accB[4] = {0, 0, 0, 0};
  for (int kc = 0; kc < CC; kc += 64) {
    __syncthreads();
    for (int l = tid; l < 16 * 64; l += 256) {
      int p = l >> 6, k = l & 63;
      tl[p][k] = t[(size_t)(px0 + p) * CC + kc + k];
    }
    for (int l = tid; l < 75 * 64; l += 256) {
      int o = l >> 6, k = l & 63;
      wl[k][o] = (o < 15) ? ow[o * CC + kc + k] : dw[(o - 15) * CC + kc + k];
    }
    __syncthreads();
#pragma unroll 8
    for (int k = 0; k < 64; ++k) {
      float w1 = wl[k][lo];
      float w2 = (lo < 11) ? wl[k][64 + lo] : 0.f;
#pragma unroll
      for (int p = 0; p < 4; ++p) {
        float tv = tl[pg * 4 + p][k];
        accA[p] = fmaf(w1, tv, accA[p]);
        accB[p] = fmaf(w2, tv, accB[p]);
      }
    }
  }
#pragma unroll
  for (int p = 0; p < 4; ++p) {
    int px = px0 + pg * 4 + p;
    int b = px / CHW, pix = px - b * CHW;
    {
      int o = lo;
      float v = accA[p];
      if (o < 15) {
        scores[(size_t)b * NANCH + (size_t)pix * CA + o] = v + ob[o];
      } else {
        int oo = o - 15;
        deltas[((size_t)b * NANCH + (size_t)pix * CA + (oo >> 2)) * 4 + (oo & 3)] = v + db[oo];
      }
    }
    if (lo < 11) {
      int oo = 64 + lo - 15;  // 49..59
      deltas[((size_t)b * NANCH + (size_t)pix * CA + (oo >> 2)) * 4 + (oo & 3)] = accB[p] + db[oo];
    }
  }
}

// ---------------- feat NCHW -> NHWC transpose (for coalesced roi_align) ----------------
__global__ __launch_bounds__(256) void transp(const float* __restrict__ in, float* __restrict__ outT) {
  __shared__ float tile[32][33];
  int b = blockIdx.z;
  int p0 = blockIdx.x * 32, c0 = blockIdx.y * 32;
  int tx = threadIdx.x, ty = threadIdx.y;
  for (int i = ty; i < 32; i += 8) {
    int p = p0 + tx;
    tile[i][tx] = (p < CHW) ? in[((size_t)b * CC + c0 + i) * CHW + p] : 0.f;
  }
  __syncthreads();
  for (int i = ty; i < 32; i += 8) {
    int p = p0 + i;
    if (p < CHW) outT[((size_t)b * CHW + p) * CC + c0 + tx] = tile[tx][i];
  }
}

// ---------------- exact top-2000 (radix threshold + bitonic sort) + proposal decode + clip ------
// grid 2 (per image), 1024 threads
__global__ __launch_bounds__(1024) void topk_props(
    const float* __restrict__ scores, const float* __restrict__ deltas,
    const int* __restrict__ isz, float* __restrict__ selB) {
  const int img = blockIdx.x;
  const int tid = threadIdx.x;
  const float* sc = scores + (size_t)img * NANCH;
  __shared__ u32 hist[256];
  __shared__ u32 s_prefix, s_need, s_cnt;
  __shared__ u64 arr[4096];

  u32 prefix = 0, need = PRE;
  for (int byte = 3; byte >= 0; --byte) {
    if (tid < 256) hist[tid] = 0;
    __syncthreads();
    for (int i = tid; i < NANCH; i += 1024) {
      u32 key = fkey(sc[i]);
      bool ok = (byte == 3) || ((key >> (8 * byte + 8)) == prefix);
      if (ok) atomicAdd(&hist[(key >> (8 * byte)) & 255], 1u);
    }
    __syncthreads();
    if (tid == 0) {
      u32 cum = 0;
      int bin;
      for (bin = 255; bin >= 0; --bin) {
        cum += hist[bin];
        if (cum >= need) break;
      }
      s_need = need - (cum - hist[bin]);
      s_prefix = (prefix << 8) | (u32)bin;
    }
    __syncthreads();
    prefix = s_prefix;
    need = s_need;
    __syncthreads();
  }
  const u32 T = prefix;  // count(key>T) < PRE <= count(key>=T)
  if (tid == 0) s_cnt = 0;
  __syncthreads();
  for (int i = tid; i < NANCH; i += 1024) {
    u32 key = fkey(sc[i]);
    if (key >= T) {
      u32 p = atomicAdd(&s_cnt, 1u);
      if (p < 4096) arr[p] = ((u64)(~key) << 32) | (u32)i;  // ascending rank = score desc, idx asc
    }
  }
  __syncthreads();
  int n = (int)(s_cnt < 4096u ? s_cnt : 4096u);
  for (int i = tid; i < 4096; i += 1024)
    if (i >= n) arr[i] = ~0ULL;
  __syncthreads();
  for (int kk = 2; kk <= 4096; kk <<= 1) {
    for (int j = kk >> 1; j > 0; j >>= 1) {
      for (int i = tid; i < 4096; i += 1024) {
        int ixj = i ^ j;
        if (ixj > i) {
          u64 a = arr[i], bb = arr[ixj];
          bool up = ((i & kk) == 0);
          if ((a > bb) == up) { arr[i] = bb; arr[ixj] = a; }
        }
      }
      __syncthreads();
    }
  }
  // decode anchor + apply deltas + clip for the top PRE (sorted)
  const float h_img = (float)isz[img * 2 + 0];
  const float w_img = (float)isz[img * 2 + 1];
  const float* dl = deltas + (size_t)img * NANCH * 4;
  for (int k = tid; k < PRE; k += 1024) {
    u32 idx = (u32)arr[k];
    int aa = (int)(idx % 15u);
    int p = (int)(idx / 15u);
    int xx = p % CW, yy = p / CW;
    double szd = 32.0 * (double)(1 << (aa / 3));
    double rr = 0.5 * (double)(1 << (aa % 3));
    double wd = szd * sqrt(1.0 / rr);
    double hd = wd * rr;
    float ax1 = (float)(xx * 16) + (float)(-wd * 0.5);
    float ax2 = (float)(xx * 16) + (float)(wd * 0.5);
    float ay1 = (float)(yy * 16) + (float)(-hd * 0.5);
    float ay2 = (float)(yy * 16) + (float)(hd * 0.5);
    float aw = ax2 - ax1, ah = ay2 - ay1;
    float cx = ax1 + 0.5f * aw, cy = ay1 + 0.5f * ah;
    float d0 = dl[(size_t)idx * 4 + 0], d1 = dl[(size_t)idx * 4 + 1];
    float d2 = dl[(size_t)idx * 4 + 2], d3 = dl[(size_t)idx * 4 + 3];
    float dwv = fminf(d2, CLIPLOG), dhv = fminf(d3, CLIPLOG);
    float pcx = d0 * aw + cx, pcy = d1 * ah + cy;
    float pw = expf(dwv) * aw, ph = expf(dhv) * ah;
    float x1 = pcx - 0.5f * pw, y1 = pcy - 0.5f * ph;
    float x2 = pcx + 0.5f * pw, y2 = pcy + 0.5f * ph;
    x1 = fminf(fmaxf(x1, 0.f), w_img);
    y1 = fminf(fmaxf(y1, 0.f), h_img);
    x2 = fminf(fmaxf(x2, 0.f), w_img);
    y2 = fminf(fmaxf(y2, 0.f), h_img);
    float* o = selB + ((size_t)img * PRE + k) * 4;
    o[0] = x1; o[1] = y1; o[2] = x2; o[3] = y2;
  }
}

// ---------------- RPN NMS suppression-mask build ----------------
// grid (8 rowblocks, 4 j-splits, 2 img), 256 threads
__global__ __launch_bounds__(256) void nms_mask(const float* __restrict__ selB, u64* __restrict__ mask) {
  const int img = blockIdx.z;
  const int jr0 = blockIdx.y * 512;
  const int i = blockIdx.x * 256 + threadIdx.x;  // 0..2047
  __shared__ float bx[PRE][4];
  __shared__ float ar[PRE];
  const int tid = threadIdx.x;
  for (int l = tid; l < PRE * 4; l += 256) bx[l >> 2][l & 3] = selB[(size_t)img * PRE * 4 + l];
  __syncthreads();
  for (int l = tid; l < PRE; l += 256) ar[l] = (bx[l][2] - bx[l][0]) * (bx[l][3] - bx[l][1]);
  __syncthreads();
  float x1 = 0, y1 = 0, x2 = 0, y2 = 0, ai = 0;
  if (i < PRE) { x1 = bx[i][0]; y1 = bx[i][1]; x2 = bx[i][2]; y2 = bx[i][3]; ai = ar[i]; }
  u64 cur = 0;
  for (int j = jr0; j < jr0 + 512; ++j) {
    bool bit = false;
    if (i < PRE && j < PRE && j > i) {
      float ltx = fmaxf(x1, bx[j][0]);
      float lty = fmaxf(y1, bx[j][1]);
      float rbx = fminf(x2, bx[j][2]);
      float rby = fminf(y2, bx[j][3]);
      float iw = fmaxf(rbx - ltx, 0.f);
      float ih = fmaxf(rby - lty, 0.f);
      float inter = iw * ih;
      float iou = inter / (ai + ar[j] - inter + 1e-9f);
      bit = iou > RPN_T;
    }
    cur |= ((u64)bit) << (j & 63);
    if ((j & 63) == 63) {
      if (i < PRE) mask[((size_t)img * PRE + i) * 32 + (j >> 6)] = cur;
      cur = 0;
    }
  }
}

// ---------------- RPN NMS serial scan + keep-list + box gather ----------------
// grid 2, 64 threads (one wave)
__global__ __launch_bounds__(64) void rpn_scan(const u64* __restrict__ mask,
    const float* __restrict__ selB, float* __restrict__ pb) {
  const int img = blockIdx.x;
  const int lane = threadIdx.x;
  const u64* mrow = mask + (size_t)img * PRE * 32;
  u64 keep = 0;
  if (lane < 31) keep = ~0ULL;
  else if (lane == 31) keep = (1ULL << 16) - 1;  // 2000 = 31*64 + 16
  for (int c = 0; c < PRE; c += 8) {
    u64 m0 = 0, m1 = 0, m2 = 0, m3 = 0, m4 = 0, m5 = 0, m6 = 0, m7 = 0;
    if (lane < 32) {
      const u64* p = mrow + (size_t)c * 32 + lane;
      m0 = p[0];   m1 = p[32];  m2 = p[64];  m3 = p[96];
      m4 = p[128]; m5 = p[160]; m6 = p[192]; m7 = p[224];
    }
#pragma unroll
    for (int k = 0; k < 8; ++k) {
      int i = c + k;
      u64 kw = __shfl(keep, i >> 6);
      if ((kw >> (i & 63)) & 1ULL) {
        u64 mm = (k == 0) ? m0 : (k == 1) ? m1 : (k == 2) ? m2 : (k == 3) ? m3
               : (k == 4) ? m4 : (k == 5) ? m5 : (k == 6) ? m6 : m7;
        keep &= ~mm;
      }
    }
  }
  __shared__ u64 kws[32];
  __shared__ int rows[POST];
  if (lane < 32) kws[lane] = keep;
  __syncthreads();
  if (lane == 0) {
    int cnt = 0;
    for (int w = 0; w < 32 && cnt < POST; ++w) {
      u64 kv = kws[w];
      while (kv && cnt < POST) {
        int b = __ffsll((unsigned long long)kv) - 1;
        int i = w * 64 + b;
        if (i < PRE) rows[cnt++] = i;
        kv &= kv - 1;
      }
    }
    for (int w = 0; w < 32 && cnt < POST; ++w) {
      u64 kv = ~kws[w];
      while (kv && cnt < POST) {
        int b = __ffsll((unsigned long long)kv) - 1;
        int i = w * 64 + b;
        if (i < PRE) rows[cnt++] = i;
        kv &= kv - 1;
      }
    }
  }
  __syncthreads();
  for (int k = lane; k < POST; k += 64) {
    int row = rows[k];
    const float* s = selB + ((size_t)img * PRE + row) * 4;
    float* d = pb + ((size_t)img * POST + k) * 4;
    d[0] = s[0]; d[1] = s[1]; d[2] = s[2]; d[3] = s[3];
  }
}

// ---------------- RoI align (7x7, mean) on NHWC feat ----------------
// grid 600 (one box), 256 threads (4 channels each)
__global__ __launch_bounds__(256) void roi_kernel(const float* __restrict__ featT,
    const float* __restrict__ pb, float* __restrict__ pooled) {
  const int box = blockIdx.x;
  const int img = box / POST;
  const int tid = threadIdx.x;
  const float scl = 0.0625f;
  float x1 = pb[box * 4 + 0] * scl, y1 = pb[box * 4 + 1] * scl;
  float x2 = pb[box * 4 + 2] * scl, y2 = pb[box * 4 + 3] * scl;
  const float* fb = featT + (size_t)img * CHW * CC;
  const int c0 = tid * 4;
  float a0 = 0, a1 = 0, a2 = 0, a3 = 0;
  for (int by = 0; by < 7; ++by) {
    float gy = ((float)by + 0.5f) / 7.0f;
    float ys = y1 + gy * (y2 - y1) - 0.5f;
    float yf = floorf(ys);
    float ly = ys - yf;
    int y0i = (int)yf;
    y0i = y0i < 0 ? 0 : (y0i > CH - 1 ? CH - 1 : y0i);
    int y1i = (y0i + 1 > CH - 1) ? CH - 1 : y0i + 1;
    for (int bx2 = 0; bx2 < 7; ++bx2) {
      float gx = ((float)bx2 + 0.5f) / 7.0f;
      float xs = x1 + gx * (x2 - x1) - 0.5f;
      float xf = floorf(xs);
      float lx = xs - xf;
      int x0i = (int)xf;
      x0i = x0i < 0 ? 0 : (x0i > CW - 1 ? CW - 1 : x0i);
      int x1i = (x0i + 1 > CW - 1) ? CW - 1 : x0i + 1;
      float w00 = (1.f - ly) * (1.f - lx), w01 = (1.f - ly) * lx;
      float w10 = ly * (1.f - lx), w11 = ly * lx;
      const float4 v00 = *reinterpret_cast<const float4*>(fb + ((size_t)y0i * CW + x0i) * CC + c0);
      const float4 v01 = *reinterpret_cast<const float4*>(fb + ((size_t)y0i * CW + x1i) * CC + c0);
      const float4 v10 = *reinterpret_cast<const float4*>(fb + ((size_t)y1i * CW + x0i) * CC + c0);
      const float4 v11 = *reinterpret_cast<const float4*>(fb + ((size_t)y1i * CW + x1i) * CC + c0);
      a0 += w00 * v00.x + w01 * v01.x + w10 * v10.x + w11 * v11.x;
      a1 += w00 * v00.y + w01 * v01.y + w10 * v10.y + w11 * v11.y;
      a2 += w00 * v00.z + w01 * v01.z + w10 * v10.z + w11 * v11.z;
      a3 += w00 * v00.w + w01 * v01.w + w10 * v10.w + w11 * v11.w;
    }
  }
  float* o = pooled + (size_t)box * CC + c0;
  o[0] = a0 / 49.f; o[1] = a1 / 49.f; o[2] = a2 / 49.f; o[3] = a3 / 49.f;
}

// ---------------- FC: logits[600][1605] = pooled @ [cls_w;box_w]^T + bias ----------------
__global__ __launch_bounds__(256) void fc_gemm(const float* __restrict__ pooled,
    const float* __restrict__ clsw, const float* __restrict__ clsb,
    const float* __restrict__ boxw, const float* __restrict__ boxb,
    float* __restrict__ logits) {
  __shared__ float As[32][65];
  __shared__ float Bs[32][65];
  const int m0 = blockIdx.x * 64;
  const int n0 = blockIdx.y * 64;
  const int tid = threadIdx.x;
  const int tm = tid & 15, tn = tid >> 4;
  float acc[4][4] = {};
  for (int kc = 0; kc < CC; kc += 32) {
    __syncthreads();
    for (int l = tid; l < 2048; l += 256) {
      int mm = l >> 5, kk = l & 31;
      int mA = m0 + mm;
      As[kk][mm] = (mA < CB * POST) ? pooled[(size_t)mA * CC + kc + kk] : 0.f;
      int nB = n0 + mm;
      float bv = 0.f;
      if (nB < 1601) bv = clsw[(size_t)nB * CC + kc + kk];
      else if (nB < GN) bv = boxw[(size_t)(nB - 1601) * CC + kc + kk];
      Bs[kk][mm] = bv;
    }
    __syncthreads();
#pragma unroll
    for (int kk = 0; kk < 32; ++kk) {
      float a[4], b[4];
#pragma unroll
      for (int ii = 0; ii < 4; ++ii) a[ii] = As[kk][tm * 4 + ii];
#pragma unroll
      for (int jj = 0; jj < 4; ++jj) b[jj] = Bs[kk][tn * 4 + jj];
#pragma unroll
      for (int ii = 0; ii < 4; ++ii)
#pragma unroll
        for (int jj = 0; jj < 4; ++jj)
          acc[ii][jj] = fmaf(a[ii], b[jj], acc[ii][jj]);
    }
  }
  for (int ii = 0; ii < 4; ++ii) {
    int mA = m0 + tm * 4 + ii;
    if (mA >= CB * POST) continue;
    for (int jj = 0; jj < 4; ++jj) {
      int nB = n0 + tn * 4 + jj;
      if (nB >= GN) continue;
      float bias = (nB < 1601) ? clsb[nB] : boxb[nB - 1601];
      logits[(size_t)mA * GN + nB] = acc[ii][jj] + bias;
    }
  }
}

// ---------------- softmax (1601) -> cls_probs (1600), msc, det box decode + clip, score gate ----
__global__ __launch_bounds__(256) void softmax_det(
    const float* __restrict__ logits, const float* __restrict__ pb,
    const int* __restrict__ isz, float* __restrict__ clsp,
    float* __restrict__ detbox, float* __restrict__ dets) {
  const int row = blockIdx.x;
  const int tid = threadIdx.x;
  const float* lr = logits + (size_t)row * GN;
  __shared__ float red[256];
  float m = -INFINITY;
  for (int c = tid; c < 1600; c += 256) m = fmaxf(m, lr[c]);
  red[tid] = m;
  __syncthreads();
  for (int s = 128; s > 0; s >>= 1) {
    if (tid < s) red[tid] = fmaxf(red[tid], red[tid + s]);
    __syncthreads();
  }
  const float m1600 = red[0];
  __syncthreads();
  const float mall = fmaxf(m1600, lr[1600]);
  float sum = 0.f;
  for (int c = tid; c < 1601; c += 256) sum += expf(lr[c] - mall);
  red[tid] = sum;
  __syncthreads();
  for (int s = 128; s > 0; s >>= 1) {
    if (tid < s) red[tid] += red[tid + s];
    __syncthreads();
  }
  const float ssum = red[0];
  for (int c = tid; c < 1600; c += 256)
    clsp[(size_t)row * NCLS + c] = expf(lr[c] - mall) / ssum;
  if (tid == 0) {
    float msc = expf(m1600 - mall) / ssum;
    int img = row / POST;
    float hh = (float)isz[img * 2 + 0], ww = (float)isz[img * 2 + 1];
    float bx1 = pb[row * 4 + 0], by1 = pb[row * 4 + 1];
    float bx2 = pb[row * 4 + 2], by2 = pb[row * 4 + 3];
    float w = bx2 - bx1, h = by2 - by1;
    float cx = bx1 + 0.5f * w, cy = by1 + 0.5f * h;
    float d0 = lr[1601] / 10.0f, d1 = lr[1602] / 10.0f;
    float d2 = fminf(lr[1603] / 5.0f, CLIPLOG), d3 = fminf(lr[1604] / 5.0f, CLIPLOG);
    float pcx = d0 * w + cx, pcy = d1 * h + cy;
    float pw = expf(d2) * w, ph = expf(d3) * h;
    float xx1 = pcx - 0.5f * pw, yy1 = pcy - 0.5f * ph;
    float xx2 = pcx + 0.5f * pw, yy2 = pcy + 0.5f * ph;
    xx1 = fminf(fmaxf(xx1, 0.f), ww);
    xx2 = fminf(fmaxf(xx2, 0.f), ww);
    yy1 = fminf(fmaxf(yy1, 0.f), hh);
    yy2 = fminf(fmaxf(yy2, 0.f), hh);
    detbox[row * 4 + 0] = xx1; detbox[row * 4 + 1] = yy1;
    detbox[row * 4 + 2] = xx2; detbox[row * 4 + 3] = yy2;
    dets[row] = msc > SCORE_T_ ? msc : -INFINITY;
  }
}

// ---------------- det NMS (sort 300 + mask + scan + top_k-exact selection) -> global rows -------
// Selection replicates top_k(where(keep, s, -inf), 100):
//   Class A: kept AND finite score, ascending sorted position (s sorted desc);
//   Class B: everything else (suppressed OR kept-with--inf), ascending position.
__global__ __launch_bounds__(512) void det_nms(const float* __restrict__ dets,
    const float* __restrict__ detbox, int* __restrict__ ridx) {
  const int img = blockIdx.x;
  const int tid = threadIdx.x;
  __shared__ u64 arr[512];
  {
    u64 v = ~0ULL;
    if (tid < POST) {
      u32 key = fkey(dets[img * POST + tid]);
      v = ((u64)(~key) << 32) | (u32)tid;  // ascending = score desc, idx asc (stable argsort(-s))
    }
    arr[tid] = v;
  }
  __syncthreads();
  for (int kk = 2; kk <= 512; kk <<= 1) {
    for (int j = kk >> 1; j > 0; j >>= 1) {
      int ixj = tid ^ j;
      if (ixj > tid) {
        u64 a = arr[tid], bb = arr[ixj];
        bool up = ((tid & kk) == 0);
        if ((a > bb) == up) { arr[tid] = bb; arr[ixj] = a; }
      }
      __syncthreads();
    }
  }
  __shared__ float bx[POST][4];
  __shared__ float ar2[POST];
  __shared__ int ord[POST];
  __shared__ unsigned char fin[POST];
  if (tid < POST) {
    int o = (int)(u32)arr[tid];
    ord[tid] = o;
    fin[tid] = (dets[img * POST + o] != -INFINITY) ? 1 : 0;
    const float* s = detbox + ((size_t)img * POST + o) * 4;
    bx[tid][0] = s[0]; bx[tid][1] = s[1]; bx[tid][2] = s[2]; bx[tid][3] = s[3];
    ar2[tid] = (s[2] - s[0]) * (s[3] - s[1]);
  }
  __syncthreads();
  __shared__ u64 sm[POST][5];
  if (tid < POST) {
    const int i = tid;
    float x1 = bx[i][0], y1 = bx[i][1], x2 = bx[i][2], y2 = bx[i][3], ai = ar2[i];
    for (int w = 0; w < 5; ++w) {
      u64 cur = 0;
      for (int b = 0; b < 64; ++b) {
        int j = w * 64 + b;
        if (j < POST && j > i) {
          float ltx = fmaxf(x1, bx[j][0]);
          float lty = fmaxf(y1, bx[j][1]);
          float rbx = fminf(x2, bx[j][2]);
          float rby = fminf(y2, bx[j][3]);
          float iw = fmaxf(rbx - ltx, 0.f);
          float ih = fmaxf(rby - lty, 0.f);
          float inter = iw * ih;
          float iou = inter / (ai + ar2[j] - inter + 1e-9f);
          if (iou > DET_T) cur |= 1ULL << b;
        }
      }
      sm[i][w] = cur;
    }
  }
  __syncthreads();
  __shared__ u64 kws[5];
  if (tid < 64) {
    u64 keep = 0;
    if (tid < 4) keep = ~0ULL;
    else if (tid == 4) keep = (1ULL << 44) - 1;  // 300 = 4*64 + 44
    for (int i = 0; i < POST; ++i) {
      u64 kw = __shfl(keep, i >> 6);
      if ((kw >> (i & 63)) & 1ULL) {
        if (tid < 5) keep &= ~sm[i][tid];
      }
    }
    if (tid < 5) kws[tid] = keep;
  }
  __syncthreads();
  __shared__ int sel[NDET];
  if (tid == 0) {
    int cnt = 0;
    for (int i = 0; i < POST && cnt < NDET; ++i) {
      bool kept = (kws[i >> 6] >> (i & 63)) & 1ULL;
      if (kept && fin[i]) sel[cnt++] = i;   // Class A: kept with finite score
    }
    for (int i = 0; i < POST && cnt < NDET; ++i) {
      bool kept = (kws[i >> 6] >> (i & 63)) & 1ULL;
      if (!(kept && fin[i])) sel[cnt++] = i;  // Class B: all -inf entries in top_k
    }
  }
  __syncthreads();
  if (tid < NDET) ridx[img * NDET + tid] = img * POST + ord[sel[tid]];
}

// ---------------- final gather into d_out: [pooled 200x1024][boxes 200x4][probs 200x1600] -------
__global__ __launch_bounds__(256) void gather_out(const int* __restrict__ ridx,
    const float* __restrict__ pooled, const float* __restrict__ pb,
    const float* __restrict__ clsp, float* __restrict__ out) {
  const int n = blockIdx.x;
  const int tid = threadIdx.x;
  const int row = ridx[n];
  for (int c = tid; c < CC; c += 256)
    out[(size_t)n * CC + c] = pooled[(size_t)row * CC + c];
  if (tid < 4)
    out[204800 + n * 4 + tid] = pb[row * 4 + tid];
  for (int c = tid; c < NCLS; c += 256)
    out[205600 + (size_t)n * NCLS + c] = clsp[(size_t)row * NCLS + c];
}

extern "C" void kernel_launch(void* const* d_in, const int* in_sizes, int n_in,
                              void* d_out, int out_size, void* d_ws, size_t ws_size,
                              hipStream_t stream) {
  (void)in_sizes; (void)n_in; (void)out_size;
  const int* isz = (const int*)d_in[1];
  const float* feat = (const float*)d_in[2];
  const float* convw = (const float*)d_in[3];
  const float* convb = (const float*)d_in[4];
  const float* objw = (const float*)d_in[5];
  const float* objb = (const float*)d_in[6];
  const float* dltw = (const float*)d_in[7];
  const float* dltb = (const float*)d_in[8];
  const float* clsw = (const float*)d_in[9];
  const float* clsb = (const float*)d_in[10];
  const float* boxw = (const float*)d_in[11];
  const float* boxb = (const float*)d_in[12];
  float* out = (float*)d_out;

  char* wsb = (char*)d_ws;
  size_t off = 0;
  auto alloc = [&](size_t bytes) -> void* {
    void* p = wsb + off;
    off = (off + bytes + 255) & ~(size_t)255;
    return p;
  };
  constexpr size_t TSZ = (size_t)CB * CHW * CC * 4;         // 31.1 MB
  float* t = (float*)alloc(TSZ);                            // partial ks=0 / t / later featT
  float* scores = (float*)alloc((size_t)CB * NANCH * 4);
  float* deltas = (float*)alloc((size_t)CB * NANCH * 4 * 4);
  float* selB = (float*)alloc((size_t)CB * PRE * 4 * 4);
  u64* mask = (u64*)alloc((size_t)CB * PRE * 32 * 8);
  float* pb = (float*)alloc((size_t)CB * POST * 4 * 4);
  float* pooled = (float*)alloc((size_t)CB * POST * CC * 4);
  float* logits = (float*)alloc((size_t)CB * POST * GN * 4);
  float* clsp = (float*)alloc((size_t)CB * POST * NCLS * 4);
  float* detbox = (float*)alloc((size_t)CB * POST * 4 * 4);
  float* dets = (float*)alloc((size_t)CB * POST * 4);
  int* ridx = (int*)alloc((size_t)CB * NDET * 4);
  if (off > ws_size) return;  // base layout must fit

  // K-split partial buffers allocated LAST: prefer 4-way, fallback 2-way, then none.
  size_t base_off = off;
  int nks = 1;
  float *p1 = t, *p2 = t, *p3 = t;
  if (base_off + 3 * (TSZ + 256) <= ws_size) {
    nks = 4;
    p1 = (float*)alloc(TSZ); p2 = (float*)alloc(TSZ); p3 = (float*)alloc(TSZ);
  } else if (base_off + (TSZ + 256) <= ws_size) {
    nks = 2;
    p1 = (float*)alloc(TSZ);
  }
  const int klen = CC / nks;

  conv3x3p<<<dim3(8 * nks, CH, CB), 256, 0, stream>>>(feat, convw, t, p1, p2, p3, klen);
  reduce_br<<<dim3((CB * CHW * CC) / 1024), 256, 0, stream>>>(p1, p2, p3, convb, t, nks);
  heads<<<dim3(CB * CHW / 16), 256, 0, stream>>>(t, objw, objb, dltw, dltb, scores, deltas);
  transp<<<dim3((CHW + 31) / 32, CC / 32, CB), dim3(32, 8), 0, stream>>>(feat, t);  // t := featT
  topk_props<<<dim3(CB), 1024, 0, stream>>>(scores, deltas, isz, selB);
  nms_mask<<<dim3(8, 4, CB), 256, 0, stream>>>(selB, mask);
  rpn_scan<<<dim3(CB), 64, 0, stream>>>(mask, selB, pb);
  roi_kernel<<<dim3(CB * POST), 256, 0, stream>>>(t, pb, pooled);
  fc_gemm<<<dim3(10, 26), 256, 0, stream>>>(pooled, clsw, clsb, boxw, boxb, logits);
  softmax_det<<<dim3(CB * POST), 256, 0, stream>>>(logits, pb, isz, clsp, detbox, dets);
  det_nms<<<dim3(CB), 512, 0, stream>>>(dets, detbox, ridx);
  gather_out<<<dim3(CB * NDET), 256, 0, stream>>>(ridx, pooled, pb, clsp, out);
}